// Round 1
// baseline (1636.631 us; speedup 1.0000x reference)
//
#include <hip/hip_runtime.h>

#define D 64
#define NGRAPH 128
#define NCLS 10
#define BN_EPS 1e-5f
#define MM_ROWS 16

// ---------------------------------------------------------------------------
// Scatter: one wave per edge; lane j adds x[src][j] into msg[dst][j].
// ---------------------------------------------------------------------------
__global__ __launch_bounds__(256) void scatter_kernel(
    const float* __restrict__ x, const int* __restrict__ ei,
    float* __restrict__ msg, int E) {
  long long tid = (long long)blockIdx.x * 256 + threadIdx.x;
  int e = (int)(tid >> 6);
  int j = (int)(tid & 63);
  if (e >= E) return;
  int s = ei[e];       // src row
  int d = ei[E + e];   // dst row
  atomicAdd(&msg[d * D + j], x[s * D + j]);
}

// ---------------------------------------------------------------------------
// Fused: h = msg @ Wrel + brel + xin @ Wroot, written IN PLACE over msg.
// Also accumulates per-feature sum / sumsq into stats[0..63] / stats[64..127].
// Block = 256 threads (4 waves). Wave g computes rows [4g..4g+3] of each
// 16-row tile; thread j = column. W staged in LDS [k][j]; row data staged
// transposed [k][r] (padded 16->20 floats, keeps 16B alignment for b128
// broadcast reads).
// ---------------------------------------------------------------------------
__global__ __launch_bounds__(256) void mm_stats_kernel(
    const float* __restrict__ msg, const float* __restrict__ xin,
    const float* __restrict__ Wrel, const float* __restrict__ brel,
    const float* __restrict__ Wroot,
    float* __restrict__ h, float* __restrict__ stats, int N) {
  __shared__ float sWrel[D][D];
  __shared__ float sWroot[D][D];
  __shared__ float sM[D][20];
  __shared__ float sX[D][20];

  int tid = threadIdx.x;
  for (int idx = tid; idx < D * D; idx += 256) {
    sWrel[idx >> 6][idx & 63] = Wrel[idx];
    sWroot[idx >> 6][idx & 63] = Wroot[idx];
  }
  int j = tid & 63;   // column
  int g = tid >> 6;   // wave id / row group
  float bj = brel[j];
  float psum = 0.f, psq = 0.f;

  int tiles = (N + MM_ROWS - 1) / MM_ROWS;
  for (int t = blockIdx.x; t < tiles; t += gridDim.x) {
    int i0 = t * MM_ROWS;
    __syncthreads();  // protect LDS from previous iteration readers
    for (int idx = tid; idx < MM_ROWS * D; idx += 256) {
      int r = idx >> 6, k = idx & 63;
      int i = i0 + r;
      float mv = 0.f, xv = 0.f;
      if (i < N) { mv = msg[i * D + k]; xv = xin[i * D + k]; }
      sM[k][r] = mv;
      sX[k][r] = xv;
    }
    __syncthreads();

    int rb = g * 4;
    float acc0 = bj, acc1 = bj, acc2 = bj, acc3 = bj;
#pragma unroll
    for (int k = 0; k < D; k++) {
      float w1 = sWrel[k][j];
      float w2 = sWroot[k][j];
      float4 m4 = *(const float4*)&sM[k][rb];
      float4 x4 = *(const float4*)&sX[k][rb];
      acc0 += m4.x * w1 + x4.x * w2;
      acc1 += m4.y * w1 + x4.y * w2;
      acc2 += m4.z * w1 + x4.z * w2;
      acc3 += m4.w * w1 + x4.w * w2;
    }
    int i = i0 + rb;
    if (i + 0 < N) { h[(i + 0) * D + j] = acc0; psum += acc0; psq += acc0 * acc0; }
    if (i + 1 < N) { h[(i + 1) * D + j] = acc1; psum += acc1; psq += acc1 * acc1; }
    if (i + 2 < N) { h[(i + 2) * D + j] = acc2; psum += acc2; psq += acc2 * acc2; }
    if (i + 3 < N) { h[(i + 3) * D + j] = acc3; psum += acc3; psq += acc3 * acc3; }
  }

  // Block reduction of stats across the 4 waves, then one atomic per column.
  __syncthreads();
  sM[j][g] = psum;
  sX[j][g] = psq;
  __syncthreads();
  if (g == 0) {
    float s = sM[j][0] + sM[j][1] + sM[j][2] + sM[j][3];
    float q = sX[j][0] + sX[j][1] + sX[j][2] + sX[j][3];
    atomicAdd(&stats[j], s);
    atomicAdd(&stats[D + j], q);
  }
}

// ---------------------------------------------------------------------------
// Fold BN stats into per-feature scale/shift.
// ---------------------------------------------------------------------------
__global__ void bn_finalize_kernel(const float* __restrict__ stats,
                                   const float* __restrict__ gamma,
                                   const float* __restrict__ beta,
                                   float* __restrict__ scsh, float fN) {
  int j = threadIdx.x;  // 64 threads
  float mean = stats[j] / fN;
  float var = stats[D + j] / fN - mean * mean;
  float sc = gamma[j] * rsqrtf(var + BN_EPS);
  scsh[j] = sc;
  scsh[D + j] = beta[j] - mean * sc;
}

// ---------------------------------------------------------------------------
// Elementwise normalize + ReLU (layers 0,1): xout = relu(h*scale + shift).
// ---------------------------------------------------------------------------
__global__ __launch_bounds__(256) void norm_relu_kernel(
    const float* __restrict__ h, const float* __restrict__ scsh,
    float* __restrict__ xout, int n) {
  int tid = blockIdx.x * 256 + threadIdx.x;
  int base = tid * 4;
  if (base >= n) return;
  int j = base & 63;
  float4 hv = *(const float4*)&h[base];
  float4 sc = *(const float4*)&scsh[j];
  float4 sh = *(const float4*)&scsh[D + j];
  float4 o;
  o.x = fmaxf(hv.x * sc.x + sh.x, 0.f);
  o.y = fmaxf(hv.y * sc.y + sh.y, 0.f);
  o.z = fmaxf(hv.z * sc.z + sh.z, 0.f);
  o.w = fmaxf(hv.w * sc.w + sh.w, 0.f);
  *(float4*)&xout[base] = o;
}

// ---------------------------------------------------------------------------
// Last layer: normalize + ReLU fused with graph mean-pool accumulation.
// batch is sorted, so run-length accumulate before atomics.
// Block handles 256 rows; thread (j, q) walks rows q, q+4, ... within block.
// ---------------------------------------------------------------------------
__global__ __launch_bounds__(256) void norm_relu_pool_kernel(
    const float* __restrict__ h, const float* __restrict__ scsh,
    const int* __restrict__ batch, float* __restrict__ pooled, int N) {
  int j = threadIdx.x & 63;
  int q = threadIdx.x >> 6;
  int i0 = blockIdx.x * 256;
  float sc = scsh[j], sh = scsh[D + j];
  int curg = -1;
  float acc = 0.f;
  for (int r = q; r < 256; r += 4) {
    int i = i0 + r;
    if (i >= N) break;
    int b = batch[i];
    float v = fmaxf(h[i * D + j] * sc + sh, 0.f);
    if (b != curg) {
      if (curg >= 0) atomicAdd(&pooled[curg * D + j], acc);
      curg = b;
      acc = v;
    } else {
      acc += v;
    }
  }
  if (curg >= 0) atomicAdd(&pooled[curg * D + j], acc);
}

// ---------------------------------------------------------------------------
// Per-graph node counts via binary search on sorted batch (no atomics).
// ---------------------------------------------------------------------------
__global__ void counts_kernel(const int* __restrict__ batch,
                              float* __restrict__ counts, int N) {
  int g = threadIdx.x;
  if (g >= NGRAPH) return;
  int lo = 0, hi = N;
  while (lo < hi) { int m = (lo + hi) >> 1; if (batch[m] < g) lo = m + 1; else hi = m; }
  int start = lo;
  lo = 0; hi = N;
  while (lo < hi) { int m = (lo + hi) >> 1; if (batch[m] <= g) lo = m + 1; else hi = m; }
  counts[g] = (float)(lo - start);
}

// ---------------------------------------------------------------------------
// Final classifier: out[g][c] = (pooled[g]/max(count,1)) . Wcls[:,c] + bcls[c]
// ---------------------------------------------------------------------------
__global__ void cls_kernel(const float* __restrict__ pooled,
                           const float* __restrict__ counts,
                           const float* __restrict__ Wcls,
                           const float* __restrict__ bcls,
                           float* __restrict__ out) {
  int tid = blockIdx.x * blockDim.x + threadIdx.x;
  if (tid >= NGRAPH * NCLS) return;
  int g = tid / NCLS, c = tid % NCLS;
  float inv = 1.f / fmaxf(counts[g], 1.f);
  float acc = bcls[c];
#pragma unroll 8
  for (int k = 0; k < D; k++) acc += pooled[g * D + k] * inv * Wcls[k * NCLS + c];
  out[g * NCLS + c] = acc;
}

// ---------------------------------------------------------------------------
extern "C" void kernel_launch(void* const* d_in, const int* in_sizes, int n_in,
                              void* d_out, int out_size, void* d_ws, size_t ws_size,
                              hipStream_t stream) {
  const float* x      = (const float*)d_in[0];
  const int*   ei     = (const int*)d_in[1];
  const int*   batch  = (const int*)d_in[2];
  const float* W_rel  = (const float*)d_in[3];
  const float* b_rel  = (const float*)d_in[4];
  const float* W_root = (const float*)d_in[5];
  const float* gamma  = (const float*)d_in[6];
  const float* beta   = (const float*)d_in[7];
  const float* W_cls  = (const float*)d_in[8];
  const float* b_cls  = (const float*)d_in[9];
  float* out = (float*)d_out;

  int E = in_sizes[1] / 2;
  int N = in_sizes[2];
  size_t nd = (size_t)N * D;

  float* msg    = (float*)d_ws;          // N*D (h written in place)
  float* xA     = msg + nd;              // N*D
  float* xB     = xA + nd;               // N*D
  float* stats  = xB + nd;               // 2*D
  float* scsh   = stats + 2 * D;         // 2*D
  float* pooled = scsh + 2 * D;          // NGRAPH*D
  float* counts = pooled + NGRAPH * D;   // NGRAPH

  hipMemsetAsync(pooled, 0, (NGRAPH * D + NGRAPH) * sizeof(float), stream);

  const float* xin = x;
  for (int l = 0; l < 3; l++) {
    hipMemsetAsync(msg, 0, nd * sizeof(float), stream);
    hipMemsetAsync(stats, 0, 2 * D * sizeof(float), stream);

    long long sc_threads = (long long)E * 64;
    int sc_blocks = (int)((sc_threads + 255) / 256);
    scatter_kernel<<<sc_blocks, 256, 0, stream>>>(xin, ei, msg, E);

    mm_stats_kernel<<<2048, 256, 0, stream>>>(msg, xin, W_rel + l * D * D,
                                              b_rel + l * D, W_root + l * D * D,
                                              msg /* h in-place */, stats, N);

    bn_finalize_kernel<<<1, 64, 0, stream>>>(stats, gamma + l * D, beta + l * D,
                                             scsh, (float)N);

    if (l < 2) {
      float* xout = (l == 0) ? xA : xB;
      int n = N * D;
      norm_relu_kernel<<<(n / 4 + 255) / 256, 256, 0, stream>>>(msg, scsh, xout, n);
      xin = xout;
    } else {
      norm_relu_pool_kernel<<<(N + 255) / 256, 256, 0, stream>>>(msg, scsh, batch,
                                                                 pooled, N);
    }
  }

  counts_kernel<<<1, 128, 0, stream>>>(batch, counts, N);
  cls_kernel<<<(NGRAPH * NCLS + 255) / 256, 256, 0, stream>>>(pooled, counts,
                                                              W_cls, b_cls, out);
}

// Round 2
// 1108.092 us; speedup vs baseline: 1.4770x; 1.4770x over previous
//
#include <hip/hip_runtime.h>

#define D 64
#define NGRAPH 128
#define NCLS 10
#define BN_EPS 1e-5f
#define MM_ROWS 16

// ===========================================================================
// CSR construction (once per call; edge list identical across layers)
// ===========================================================================

// Degree histogram of dst.
__global__ __launch_bounds__(256) void hist_kernel(
    const int* __restrict__ ei, int* __restrict__ deg, int E) {
  int e = blockIdx.x * 256 + threadIdx.x;
  if (e >= E) return;
  atomicAdd(&deg[ei[E + e]], 1);
}

// Block-level exclusive scan: 1024 elements/block (4/thread).
__global__ __launch_bounds__(256) void scan1_kernel(
    const int* __restrict__ deg, int* __restrict__ row_start,
    int* __restrict__ bsum, int N) {
  __shared__ int s[256];
  int t = threadIdx.x;
  int base = blockIdx.x * 1024 + t * 4;
  int v0 = (base + 0 < N) ? deg[base + 0] : 0;
  int v1 = (base + 1 < N) ? deg[base + 1] : 0;
  int v2 = (base + 2 < N) ? deg[base + 2] : 0;
  int v3 = (base + 3 < N) ? deg[base + 3] : 0;
  s[t] = v0 + v1 + v2 + v3;
  __syncthreads();
  for (int off = 1; off < 256; off <<= 1) {
    int add = (t >= off) ? s[t - off] : 0;
    __syncthreads();
    s[t] += add;
    __syncthreads();
  }
  int excl = (t == 0) ? 0 : s[t - 1];
  if (t == 255) bsum[blockIdx.x] = s[255];
  if (base + 0 < N) row_start[base + 0] = excl;
  if (base + 1 < N) row_start[base + 1] = excl + v0;
  if (base + 2 < N) row_start[base + 2] = excl + v0 + v1;
  if (base + 3 < N) row_start[base + 3] = excl + v0 + v1 + v2;
}

// Exclusive scan of block sums (nb <= 1024), plus write row_start[N] = E.
__global__ __launch_bounds__(1024) void scan2_kernel(
    int* __restrict__ bsum, int* __restrict__ row_start, int nb, int E, int N) {
  __shared__ int s[1024];
  int t = threadIdx.x;
  s[t] = (t < nb) ? bsum[t] : 0;
  __syncthreads();
  for (int off = 1; off < 1024; off <<= 1) {
    int add = (t >= off) ? s[t - off] : 0;
    __syncthreads();
    s[t] += add;
    __syncthreads();
  }
  if (t < nb) bsum[t] = (t == 0) ? 0 : s[t - 1];
  if (t == 0) row_start[N] = E;
}

// Add scanned block offsets.
__global__ __launch_bounds__(256) void scan3_kernel(
    int* __restrict__ row_start, const int* __restrict__ bsum, int N) {
  int off = bsum[blockIdx.x];
  int base = blockIdx.x * 1024 + threadIdx.x * 4;
#pragma unroll
  for (int k = 0; k < 4; k++)
    if (base + k < N) row_start[base + k] += off;
}

// Place src ids into CSR slots.
__global__ __launch_bounds__(256) void fill_kernel(
    const int* __restrict__ ei, const int* __restrict__ row_start,
    int* __restrict__ cursor, int* __restrict__ csr_src, int E) {
  int e = blockIdx.x * 256 + threadIdx.x;
  if (e >= E) return;
  int s = ei[e];
  int d = ei[E + e];
  int pos = atomicAdd(&cursor[d], 1);
  csr_src[row_start[d] + pos] = s;
}

// ===========================================================================
// Gather: msg[i] = sum over in-edges of x[src]. One wave per node, lane=feat.
// ===========================================================================
__global__ __launch_bounds__(256) void gather_kernel(
    const float* __restrict__ x, const int* __restrict__ csr_src,
    const int* __restrict__ row_start, float* __restrict__ msg, int N) {
  int i = blockIdx.x * 4 + (threadIdx.x >> 6);
  int j = threadIdx.x & 63;
  if (i >= N) return;
  int e0 = row_start[i], e1 = row_start[i + 1];
  float acc = 0.f;
  int e = e0;
  for (; e + 3 < e1; e += 4) {
    int s0 = csr_src[e + 0], s1 = csr_src[e + 1];
    int s2 = csr_src[e + 2], s3 = csr_src[e + 3];
    acc += x[s0 * D + j];
    acc += x[s1 * D + j];
    acc += x[s2 * D + j];
    acc += x[s3 * D + j];
  }
  for (; e < e1; e++) acc += x[csr_src[e] * D + j];
  msg[i * D + j] = acc;
}

// ===========================================================================
// Fused: h = msg @ Wrel + brel + xin @ Wroot, in place over msg; BN stats.
// ===========================================================================
__global__ __launch_bounds__(256) void mm_stats_kernel(
    const float* __restrict__ msg, const float* __restrict__ xin,
    const float* __restrict__ Wrel, const float* __restrict__ brel,
    const float* __restrict__ Wroot,
    float* __restrict__ h, float* __restrict__ stats, int N) {
  __shared__ float sWrel[D][D];
  __shared__ float sWroot[D][D];
  __shared__ float sM[D][20];
  __shared__ float sX[D][20];

  int tid = threadIdx.x;
  for (int idx = tid; idx < D * D; idx += 256) {
    sWrel[idx >> 6][idx & 63] = Wrel[idx];
    sWroot[idx >> 6][idx & 63] = Wroot[idx];
  }
  int j = tid & 63;   // column
  int g = tid >> 6;   // wave id / row group
  float bj = brel[j];
  float psum = 0.f, psq = 0.f;

  int tiles = (N + MM_ROWS - 1) / MM_ROWS;
  for (int t = blockIdx.x; t < tiles; t += gridDim.x) {
    int i0 = t * MM_ROWS;
    __syncthreads();
    for (int idx = tid; idx < MM_ROWS * D; idx += 256) {
      int r = idx >> 6, k = idx & 63;
      int i = i0 + r;
      float mv = 0.f, xv = 0.f;
      if (i < N) { mv = msg[i * D + k]; xv = xin[i * D + k]; }
      sM[k][r] = mv;
      sX[k][r] = xv;
    }
    __syncthreads();

    int rb = g * 4;
    float acc0 = bj, acc1 = bj, acc2 = bj, acc3 = bj;
#pragma unroll
    for (int k = 0; k < D; k++) {
      float w1 = sWrel[k][j];
      float w2 = sWroot[k][j];
      float4 m4 = *(const float4*)&sM[k][rb];
      float4 x4 = *(const float4*)&sX[k][rb];
      acc0 += m4.x * w1 + x4.x * w2;
      acc1 += m4.y * w1 + x4.y * w2;
      acc2 += m4.z * w1 + x4.z * w2;
      acc3 += m4.w * w1 + x4.w * w2;
    }
    int i = i0 + rb;
    if (i + 0 < N) { h[(i + 0) * D + j] = acc0; psum += acc0; psq += acc0 * acc0; }
    if (i + 1 < N) { h[(i + 1) * D + j] = acc1; psum += acc1; psq += acc1 * acc1; }
    if (i + 2 < N) { h[(i + 2) * D + j] = acc2; psum += acc2; psq += acc2 * acc2; }
    if (i + 3 < N) { h[(i + 3) * D + j] = acc3; psum += acc3; psq += acc3 * acc3; }
  }

  __syncthreads();
  sM[j][g] = psum;
  sX[j][g] = psq;
  __syncthreads();
  if (g == 0) {
    float s = sM[j][0] + sM[j][1] + sM[j][2] + sM[j][3];
    float q = sX[j][0] + sX[j][1] + sX[j][2] + sX[j][3];
    atomicAdd(&stats[j], s);
    atomicAdd(&stats[D + j], q);
  }
}

// ---------------------------------------------------------------------------
__global__ void bn_finalize_kernel(const float* __restrict__ stats,
                                   const float* __restrict__ gamma,
                                   const float* __restrict__ beta,
                                   float* __restrict__ scsh, float fN) {
  int j = threadIdx.x;  // 64 threads
  float mean = stats[j] / fN;
  float var = stats[D + j] / fN - mean * mean;
  float sc = gamma[j] * rsqrtf(var + BN_EPS);
  scsh[j] = sc;
  scsh[D + j] = beta[j] - mean * sc;
}

// ---------------------------------------------------------------------------
__global__ __launch_bounds__(256) void norm_relu_kernel(
    const float* __restrict__ h, const float* __restrict__ scsh,
    float* __restrict__ xout, int n) {
  int tid = blockIdx.x * 256 + threadIdx.x;
  int base = tid * 4;
  if (base >= n) return;
  int j = base & 63;
  float4 hv = *(const float4*)&h[base];
  float4 sc = *(const float4*)&scsh[j];
  float4 sh = *(const float4*)&scsh[D + j];
  float4 o;
  o.x = fmaxf(hv.x * sc.x + sh.x, 0.f);
  o.y = fmaxf(hv.y * sc.y + sh.y, 0.f);
  o.z = fmaxf(hv.z * sc.z + sh.z, 0.f);
  o.w = fmaxf(hv.w * sc.w + sh.w, 0.f);
  *(float4*)&xout[base] = o;
}

// ---------------------------------------------------------------------------
__global__ __launch_bounds__(256) void norm_relu_pool_kernel(
    const float* __restrict__ h, const float* __restrict__ scsh,
    const int* __restrict__ batch, float* __restrict__ pooled, int N) {
  int j = threadIdx.x & 63;
  int q = threadIdx.x >> 6;
  int i0 = blockIdx.x * 256;
  float sc = scsh[j], sh = scsh[D + j];
  int curg = -1;
  float acc = 0.f;
  for (int r = q; r < 256; r += 4) {
    int i = i0 + r;
    if (i >= N) break;
    int b = batch[i];
    float v = fmaxf(h[i * D + j] * sc + sh, 0.f);
    if (b != curg) {
      if (curg >= 0) atomicAdd(&pooled[curg * D + j], acc);
      curg = b;
      acc = v;
    } else {
      acc += v;
    }
  }
  if (curg >= 0) atomicAdd(&pooled[curg * D + j], acc);
}

// ---------------------------------------------------------------------------
__global__ void counts_kernel(const int* __restrict__ batch,
                              float* __restrict__ counts, int N) {
  int g = threadIdx.x;
  if (g >= NGRAPH) return;
  int lo = 0, hi = N;
  while (lo < hi) { int m = (lo + hi) >> 1; if (batch[m] < g) lo = m + 1; else hi = m; }
  int start = lo;
  lo = 0; hi = N;
  while (lo < hi) { int m = (lo + hi) >> 1; if (batch[m] <= g) lo = m + 1; else hi = m; }
  counts[g] = (float)(lo - start);
}

// ---------------------------------------------------------------------------
__global__ void cls_kernel(const float* __restrict__ pooled,
                           const float* __restrict__ counts,
                           const float* __restrict__ Wcls,
                           const float* __restrict__ bcls,
                           float* __restrict__ out) {
  int tid = blockIdx.x * blockDim.x + threadIdx.x;
  if (tid >= NGRAPH * NCLS) return;
  int g = tid / NCLS, c = tid % NCLS;
  float inv = 1.f / fmaxf(counts[g], 1.f);
  float acc = bcls[c];
#pragma unroll 8
  for (int k = 0; k < D; k++) acc += pooled[g * D + k] * inv * Wcls[k * NCLS + c];
  out[g * NCLS + c] = acc;
}

// ---------------------------------------------------------------------------
extern "C" void kernel_launch(void* const* d_in, const int* in_sizes, int n_in,
                              void* d_out, int out_size, void* d_ws, size_t ws_size,
                              hipStream_t stream) {
  const float* x      = (const float*)d_in[0];
  const int*   ei     = (const int*)d_in[1];
  const int*   batch  = (const int*)d_in[2];
  const float* W_rel  = (const float*)d_in[3];
  const float* b_rel  = (const float*)d_in[4];
  const float* W_root = (const float*)d_in[5];
  const float* gamma  = (const float*)d_in[6];
  const float* beta   = (const float*)d_in[7];
  const float* W_cls  = (const float*)d_in[8];
  const float* b_cls  = (const float*)d_in[9];
  float* out = (float*)d_out;

  int E = in_sizes[1] / 2;
  int N = in_sizes[2];
  size_t nd = (size_t)N * D;
  int nb = (N + 1023) / 1024;  // scan blocks (<=1024 assumed; N=100k -> 98)

  // Workspace layout (floats then ints).
  float* bufA   = (float*)d_ws;          // N*D: gather target / h in place
  float* bufB   = bufA + nd;             // N*D: normalized x ping-pong
  float* stats  = bufB + nd;             // 2*D
  float* scsh   = stats + 2 * D;         // 2*D
  float* pooled = scsh + 2 * D;          // NGRAPH*D
  float* counts = pooled + NGRAPH * D;   // NGRAPH
  int* deg       = (int*)(counts + NGRAPH);
  int* cursor    = deg + N;
  int* row_start = cursor + N;           // N+1
  int* bsum      = row_start + N + 1;    // nb
  int* csr_src   = bsum + ((nb + 3) & ~3);  // E

  // ---- CSR build (once) ----
  hipMemsetAsync(deg, 0, 2 * N * sizeof(int), stream);  // deg + cursor
  hipMemsetAsync(pooled, 0, (NGRAPH * D + NGRAPH) * sizeof(float), stream);
  hist_kernel<<<(E + 255) / 256, 256, 0, stream>>>(ei, deg, E);
  scan1_kernel<<<nb, 256, 0, stream>>>(deg, row_start, bsum, N);
  scan2_kernel<<<1, 1024, 0, stream>>>(bsum, row_start, nb, E, N);
  scan3_kernel<<<nb, 256, 0, stream>>>(row_start, bsum, N);
  fill_kernel<<<(E + 255) / 256, 256, 0, stream>>>(ei, row_start, cursor, csr_src, E);

  // ---- Layers ----
  const float* xin = x;
  for (int l = 0; l < 3; l++) {
    hipMemsetAsync(stats, 0, 2 * D * sizeof(float), stream);

    gather_kernel<<<(N + 3) / 4, 256, 0, stream>>>(xin, csr_src, row_start, bufA, N);

    mm_stats_kernel<<<2048, 256, 0, stream>>>(bufA, xin, W_rel + l * D * D,
                                              b_rel + l * D, W_root + l * D * D,
                                              bufA /* h in-place */, stats, N);

    bn_finalize_kernel<<<1, 64, 0, stream>>>(stats, gamma + l * D, beta + l * D,
                                             scsh, (float)N);

    if (l < 2) {
      int n = N * D;
      norm_relu_kernel<<<(n / 4 + 255) / 256, 256, 0, stream>>>(bufA, scsh, bufB, n);
      xin = bufB;
    } else {
      norm_relu_pool_kernel<<<(N + 255) / 256, 256, 0, stream>>>(bufA, scsh, batch,
                                                                 pooled, N);
    }
  }

  counts_kernel<<<1, 128, 0, stream>>>(batch, counts, N);
  cls_kernel<<<(NGRAPH * NCLS + 255) / 256, 256, 0, stream>>>(pooled, counts,
                                                              W_cls, b_cls, out);
}

// Round 3
// 1053.988 us; speedup vs baseline: 1.5528x; 1.0513x over previous
//
#include <hip/hip_runtime.h>

#define D 64
#define NGRAPH 128
#define NCLS 10
#define BN_EPS 1e-5f

// ===========================================================================
// CSR construction (once per call; edge list identical across layers)
// ===========================================================================
__global__ __launch_bounds__(256) void hist_kernel(
    const int* __restrict__ ei, int* __restrict__ deg, int E) {
  int e = blockIdx.x * 256 + threadIdx.x;
  if (e >= E) return;
  atomicAdd(&deg[ei[E + e]], 1);
}

__global__ __launch_bounds__(256) void scan1_kernel(
    const int* __restrict__ deg, int* __restrict__ row_start,
    int* __restrict__ bsum, int N) {
  __shared__ int s[256];
  int t = threadIdx.x;
  int base = blockIdx.x * 1024 + t * 4;
  int v0 = (base + 0 < N) ? deg[base + 0] : 0;
  int v1 = (base + 1 < N) ? deg[base + 1] : 0;
  int v2 = (base + 2 < N) ? deg[base + 2] : 0;
  int v3 = (base + 3 < N) ? deg[base + 3] : 0;
  s[t] = v0 + v1 + v2 + v3;
  __syncthreads();
  for (int off = 1; off < 256; off <<= 1) {
    int add = (t >= off) ? s[t - off] : 0;
    __syncthreads();
    s[t] += add;
    __syncthreads();
  }
  int excl = (t == 0) ? 0 : s[t - 1];
  if (t == 255) bsum[blockIdx.x] = s[255];
  if (base + 0 < N) row_start[base + 0] = excl;
  if (base + 1 < N) row_start[base + 1] = excl + v0;
  if (base + 2 < N) row_start[base + 2] = excl + v0 + v1;
  if (base + 3 < N) row_start[base + 3] = excl + v0 + v1 + v2;
}

__global__ __launch_bounds__(1024) void scan2_kernel(
    int* __restrict__ bsum, int* __restrict__ row_start, int nb, int E, int N) {
  __shared__ int s[1024];
  int t = threadIdx.x;
  s[t] = (t < nb) ? bsum[t] : 0;
  __syncthreads();
  for (int off = 1; off < 1024; off <<= 1) {
    int add = (t >= off) ? s[t - off] : 0;
    __syncthreads();
    s[t] += add;
    __syncthreads();
  }
  if (t < nb) bsum[t] = (t == 0) ? 0 : s[t - 1];
  if (t == 0) row_start[N] = E;
}

__global__ __launch_bounds__(256) void scan3_kernel(
    int* __restrict__ row_start, const int* __restrict__ bsum, int N) {
  int off = bsum[blockIdx.x];
  int base = blockIdx.x * 1024 + threadIdx.x * 4;
#pragma unroll
  for (int k = 0; k < 4; k++)
    if (base + k < N) row_start[base + k] += off;
}

__global__ __launch_bounds__(256) void fill_kernel(
    const int* __restrict__ ei, const int* __restrict__ row_start,
    int* __restrict__ cursor, int* __restrict__ csr_src, int E) {
  int e = blockIdx.x * 256 + threadIdx.x;
  if (e >= E) return;
  int s = ei[e];
  int d = ei[E + e];
  int pos = atomicAdd(&cursor[d], 1);
  csr_src[row_start[d] + pos] = s;
}

// ===========================================================================
// Weight transpose prep: wT[l][0][j][k] = Wrel[l][k][j], wT[l][1][j][k] = Wroot.
// Column-contiguous so the mm kernel's uniform reads become s_load.
// ===========================================================================
__global__ __launch_bounds__(256) void transpose_w_kernel(
    const float* __restrict__ Wrel, const float* __restrict__ Wroot,
    float* __restrict__ wT) {
  int l = blockIdx.x;  // 0..2
  for (int idx = threadIdx.x; idx < D * D; idx += 256) {
    int k = idx >> 6, j = idx & 63;
    wT[l * 2 * D * D + j * D + k] = Wrel[l * D * D + k * D + j];
    wT[l * 2 * D * D + D * D + j * D + k] = Wroot[l * D * D + k * D + j];
  }
}

// ===========================================================================
// Gather: msg[i] = sum over in-edges of x[src]. One wave per node, lane=feat.
// ===========================================================================
__global__ __launch_bounds__(256) void gather_kernel(
    const float* __restrict__ x, const int* __restrict__ csr_src,
    const int* __restrict__ row_start, float* __restrict__ msg, int N) {
  int i = blockIdx.x * 4 + (threadIdx.x >> 6);
  int j = threadIdx.x & 63;
  if (i >= N) return;
  int e0 = row_start[i], e1 = row_start[i + 1];
  float acc = 0.f;
  int e = e0;
  for (; e + 3 < e1; e += 4) {
    int s0 = csr_src[e + 0], s1 = csr_src[e + 1];
    int s2 = csr_src[e + 2], s3 = csr_src[e + 3];
    acc += x[s0 * D + j];
    acc += x[s1 * D + j];
    acc += x[s2 * D + j];
    acc += x[s3 * D + j];
  }
  for (; e < e1; e++) acc += x[csr_src[e] * D + j];
  msg[i * D + j] = acc;
}

// ===========================================================================
// mm: h = msg @ Wrel + brel + xin @ Wroot, IN PLACE over msg.
// Lane = node row; full msg/x rows live in VGPRs (32 x dwordx4 loads).
// Weights read via wave-uniform indices from transposed copies -> s_load ->
// v_fmac with SGPR operand. Inner loop has ZERO LDS traffic.
// ===========================================================================
__global__ __launch_bounds__(256) void mm_reg_kernel(
    const float* __restrict__ msg, const float* __restrict__ xin,
    const float* __restrict__ wrelT, const float* __restrict__ wrootT,
    const float* __restrict__ brel, float* __restrict__ h, int N) {
  int r = blockIdx.x * 256 + threadIdx.x;  // one row per thread
  bool valid = r < N;
  int rr = valid ? r : N - 1;

  float4 m[16], xr[16];
  const float4* mp = (const float4*)(msg + (size_t)rr * D);
  const float4* xp = (const float4*)(xin + (size_t)rr * D);
#pragma unroll
  for (int q = 0; q < 16; q++) { m[q] = mp[q]; xr[q] = xp[q]; }

  float4* hp = (float4*)(h + (size_t)rr * D);

#pragma unroll 1
  for (int jb = 0; jb < 16; jb++) {
    float4 acc;
    acc.x = brel[jb * 4 + 0];
    acc.y = brel[jb * 4 + 1];
    acc.z = brel[jb * 4 + 2];
    acc.w = brel[jb * 4 + 3];
    const float* w0 = wrelT + (jb * 4 + 0) * D;
    const float* w1 = wrelT + (jb * 4 + 1) * D;
    const float* w2 = wrelT + (jb * 4 + 2) * D;
    const float* w3 = wrelT + (jb * 4 + 3) * D;
    const float* u0 = wrootT + (jb * 4 + 0) * D;
    const float* u1 = wrootT + (jb * 4 + 1) * D;
    const float* u2 = wrootT + (jb * 4 + 2) * D;
    const float* u3 = wrootT + (jb * 4 + 3) * D;
#pragma unroll
    for (int q = 0; q < 16; q++) {
      float4 mv = m[q];
      float4 xv = xr[q];
      int k = q * 4;
      acc.x += mv.x * w0[k + 0] + mv.y * w0[k + 1] + mv.z * w0[k + 2] + mv.w * w0[k + 3];
      acc.y += mv.x * w1[k + 0] + mv.y * w1[k + 1] + mv.z * w1[k + 2] + mv.w * w1[k + 3];
      acc.z += mv.x * w2[k + 0] + mv.y * w2[k + 1] + mv.z * w2[k + 2] + mv.w * w2[k + 3];
      acc.w += mv.x * w3[k + 0] + mv.y * w3[k + 1] + mv.z * w3[k + 2] + mv.w * w3[k + 3];
      acc.x += xv.x * u0[k + 0] + xv.y * u0[k + 1] + xv.z * u0[k + 2] + xv.w * u0[k + 3];
      acc.y += xv.x * u1[k + 0] + xv.y * u1[k + 1] + xv.z * u1[k + 2] + xv.w * u1[k + 3];
      acc.z += xv.x * u2[k + 0] + xv.y * u2[k + 1] + xv.z * u2[k + 2] + xv.w * u2[k + 3];
      acc.w += xv.x * u3[k + 0] + xv.y * u3[k + 1] + xv.z * u3[k + 2] + xv.w * u3[k + 3];
    }
    if (valid) hp[jb] = acc;
  }
}

// ===========================================================================
// BN stats: per-column sum/sumsq over h. Coalesced float4 reads.
// ===========================================================================
__global__ __launch_bounds__(256) void stats_kernel(
    const float* __restrict__ h, float* __restrict__ stats, int N) {
  __shared__ float rsum[16][D];
  __shared__ float rsq[16][D];
  int jq = threadIdx.x & 15;   // column quad
  int rg = threadIdx.x >> 4;   // row group 0..15
  float4 s = {0.f, 0.f, 0.f, 0.f}, q2 = {0.f, 0.f, 0.f, 0.f};
  for (int i = blockIdx.x * 16 + rg; i < N; i += gridDim.x * 16) {
    float4 v = *(const float4*)(h + (size_t)i * D + jq * 4);
    s.x += v.x; s.y += v.y; s.z += v.z; s.w += v.w;
    q2.x += v.x * v.x; q2.y += v.y * v.y; q2.z += v.z * v.z; q2.w += v.w * v.w;
  }
  rsum[rg][jq * 4 + 0] = s.x;  rsum[rg][jq * 4 + 1] = s.y;
  rsum[rg][jq * 4 + 2] = s.z;  rsum[rg][jq * 4 + 3] = s.w;
  rsq[rg][jq * 4 + 0] = q2.x;  rsq[rg][jq * 4 + 1] = q2.y;
  rsq[rg][jq * 4 + 2] = q2.z;  rsq[rg][jq * 4 + 3] = q2.w;
  __syncthreads();
  int t = threadIdx.x;
  if (t < D) {
    float ss = 0.f, qq = 0.f;
#pragma unroll
    for (int g = 0; g < 16; g++) { ss += rsum[g][t]; qq += rsq[g][t]; }
    atomicAdd(&stats[t], ss);
    atomicAdd(&stats[D + t], qq);
  }
}

// ---------------------------------------------------------------------------
__global__ void bn_finalize_kernel(const float* __restrict__ stats,
                                   const float* __restrict__ gamma,
                                   const float* __restrict__ beta,
                                   float* __restrict__ scsh, float fN) {
  int j = threadIdx.x;  // 64 threads
  float mean = stats[j] / fN;
  float var = stats[D + j] / fN - mean * mean;
  float sc = gamma[j] * rsqrtf(var + BN_EPS);
  scsh[j] = sc;
  scsh[D + j] = beta[j] - mean * sc;
}

// ---------------------------------------------------------------------------
__global__ __launch_bounds__(256) void norm_relu_kernel(
    const float* __restrict__ h, const float* __restrict__ scsh,
    float* __restrict__ xout, int n) {
  int tid = blockIdx.x * 256 + threadIdx.x;
  int base = tid * 4;
  if (base >= n) return;
  int j = base & 63;
  float4 hv = *(const float4*)&h[base];
  float4 sc = *(const float4*)&scsh[j];
  float4 sh = *(const float4*)&scsh[D + j];
  float4 o;
  o.x = fmaxf(hv.x * sc.x + sh.x, 0.f);
  o.y = fmaxf(hv.y * sc.y + sh.y, 0.f);
  o.z = fmaxf(hv.z * sc.z + sh.z, 0.f);
  o.w = fmaxf(hv.w * sc.w + sh.w, 0.f);
  *(float4*)&xout[base] = o;
}

// ---------------------------------------------------------------------------
__global__ __launch_bounds__(256) void norm_relu_pool_kernel(
    const float* __restrict__ h, const float* __restrict__ scsh,
    const int* __restrict__ batch, float* __restrict__ pooled, int N) {
  int j = threadIdx.x & 63;
  int q = threadIdx.x >> 6;
  int i0 = blockIdx.x * 256;
  float sc = scsh[j], sh = scsh[D + j];
  int curg = -1;
  float acc = 0.f;
  for (int r = q; r < 256; r += 4) {
    int i = i0 + r;
    if (i >= N) break;
    int b = batch[i];
    float v = fmaxf(h[i * D + j] * sc + sh, 0.f);
    if (b != curg) {
      if (curg >= 0) atomicAdd(&pooled[curg * D + j], acc);
      curg = b;
      acc = v;
    } else {
      acc += v;
    }
  }
  if (curg >= 0) atomicAdd(&pooled[curg * D + j], acc);
}

// ---------------------------------------------------------------------------
__global__ void counts_kernel(const int* __restrict__ batch,
                              float* __restrict__ counts, int N) {
  int g = threadIdx.x;
  if (g >= NGRAPH) return;
  int lo = 0, hi = N;
  while (lo < hi) { int m = (lo + hi) >> 1; if (batch[m] < g) lo = m + 1; else hi = m; }
  int start = lo;
  lo = 0; hi = N;
  while (lo < hi) { int m = (lo + hi) >> 1; if (batch[m] <= g) lo = m + 1; else hi = m; }
  counts[g] = (float)(lo - start);
}

// ---------------------------------------------------------------------------
__global__ void cls_kernel(const float* __restrict__ pooled,
                           const float* __restrict__ counts,
                           const float* __restrict__ Wcls,
                           const float* __restrict__ bcls,
                           float* __restrict__ out) {
  int tid = blockIdx.x * blockDim.x + threadIdx.x;
  if (tid >= NGRAPH * NCLS) return;
  int g = tid / NCLS, c = tid % NCLS;
  float inv = 1.f / fmaxf(counts[g], 1.f);
  float acc = bcls[c];
#pragma unroll 8
  for (int k = 0; k < D; k++) acc += pooled[g * D + k] * inv * Wcls[k * NCLS + c];
  out[g * NCLS + c] = acc;
}

// ---------------------------------------------------------------------------
extern "C" void kernel_launch(void* const* d_in, const int* in_sizes, int n_in,
                              void* d_out, int out_size, void* d_ws, size_t ws_size,
                              hipStream_t stream) {
  const float* x      = (const float*)d_in[0];
  const int*   ei     = (const int*)d_in[1];
  const int*   batch  = (const int*)d_in[2];
  const float* W_rel  = (const float*)d_in[3];
  const float* b_rel  = (const float*)d_in[4];
  const float* W_root = (const float*)d_in[5];
  const float* gamma  = (const float*)d_in[6];
  const float* beta   = (const float*)d_in[7];
  const float* W_cls  = (const float*)d_in[8];
  const float* b_cls  = (const float*)d_in[9];
  float* out = (float*)d_out;

  int E = in_sizes[1] / 2;
  int N = in_sizes[2];
  size_t nd = (size_t)N * D;
  int nb = (N + 1023) / 1024;

  // Workspace layout.
  float* bufA   = (float*)d_ws;            // N*D: gather target / h in place
  float* bufB   = bufA + nd;               // N*D: normalized x ping-pong
  float* stats  = bufB + nd;               // 2*D
  float* scsh   = stats + 2 * D;           // 2*D
  float* pooled = scsh + 2 * D;            // NGRAPH*D
  float* counts = pooled + NGRAPH * D;     // NGRAPH
  float* wT     = counts + NGRAPH;         // 3 layers * 2 mats * 64*64
  int* deg       = (int*)(wT + 3 * 2 * D * D);
  int* cursor    = deg + N;
  int* row_start = cursor + N;             // N+1
  int* bsum      = row_start + N + 1;      // nb
  int* csr_src   = bsum + ((nb + 3) & ~3); // E

  // ---- Once-per-call prep ----
  hipMemsetAsync(deg, 0, 2 * N * sizeof(int), stream);  // deg + cursor
  hipMemsetAsync(pooled, 0, (NGRAPH * D + NGRAPH) * sizeof(float), stream);
  hist_kernel<<<(E + 255) / 256, 256, 0, stream>>>(ei, deg, E);
  scan1_kernel<<<nb, 256, 0, stream>>>(deg, row_start, bsum, N);
  scan2_kernel<<<1, 1024, 0, stream>>>(bsum, row_start, nb, E, N);
  scan3_kernel<<<nb, 256, 0, stream>>>(row_start, bsum, N);
  fill_kernel<<<(E + 255) / 256, 256, 0, stream>>>(ei, row_start, cursor, csr_src, E);
  transpose_w_kernel<<<3, 256, 0, stream>>>(W_rel, W_root, wT);

  // ---- Layers ----
  const float* xin = x;
  for (int l = 0; l < 3; l++) {
    hipMemsetAsync(stats, 0, 2 * D * sizeof(float), stream);

    gather_kernel<<<(N + 3) / 4, 256, 0, stream>>>(xin, csr_src, row_start, bufA, N);

    const float* wrelT  = wT + l * 2 * D * D;
    const float* wrootT = wrelT + D * D;
    mm_reg_kernel<<<(N + 255) / 256, 256, 0, stream>>>(
        bufA, xin, wrelT, wrootT, b_rel + l * D, bufA /* in place */, N);

    stats_kernel<<<256, 256, 0, stream>>>(bufA, stats, N);

    bn_finalize_kernel<<<1, 64, 0, stream>>>(stats, gamma + l * D, beta + l * D,
                                             scsh, (float)N);

    if (l < 2) {
      int n = N * D;
      norm_relu_kernel<<<(n / 4 + 255) / 256, 256, 0, stream>>>(bufA, scsh, bufB, n);
      xin = bufB;
    } else {
      norm_relu_pool_kernel<<<(N + 255) / 256, 256, 0, stream>>>(bufA, scsh, batch,
                                                                 pooled, N);
    }
  }

  counts_kernel<<<1, 128, 0, stream>>>(batch, counts, N);
  cls_kernel<<<(NGRAPH * NCLS + 255) / 256, 256, 0, stream>>>(pooled, counts,
                                                              W_cls, b_cls, out);
}

// Round 4
// 901.878 us; speedup vs baseline: 1.8147x; 1.1687x over previous
//
#include <hip/hip_runtime.h>

#define D 64
#define NGRAPH 128
#define NCLS 10
#define BN_EPS 1e-5f

// ===========================================================================
// CSR construction (once per call; edge list identical across layers)
// ===========================================================================
__global__ __launch_bounds__(256) void hist_kernel(
    const int* __restrict__ ei, int* __restrict__ deg, int E) {
  int e = blockIdx.x * 256 + threadIdx.x;
  if (e >= E) return;
  atomicAdd(&deg[ei[E + e]], 1);
}

__global__ __launch_bounds__(256) void scan1_kernel(
    const int* __restrict__ deg, int* __restrict__ row_start,
    int* __restrict__ bsum, int N) {
  __shared__ int s[256];
  int t = threadIdx.x;
  int base = blockIdx.x * 1024 + t * 4;
  int v0 = (base + 0 < N) ? deg[base + 0] : 0;
  int v1 = (base + 1 < N) ? deg[base + 1] : 0;
  int v2 = (base + 2 < N) ? deg[base + 2] : 0;
  int v3 = (base + 3 < N) ? deg[base + 3] : 0;
  s[t] = v0 + v1 + v2 + v3;
  __syncthreads();
  for (int off = 1; off < 256; off <<= 1) {
    int add = (t >= off) ? s[t - off] : 0;
    __syncthreads();
    s[t] += add;
    __syncthreads();
  }
  int excl = (t == 0) ? 0 : s[t - 1];
  if (t == 255) bsum[blockIdx.x] = s[255];
  if (base + 0 < N) row_start[base + 0] = excl;
  if (base + 1 < N) row_start[base + 1] = excl + v0;
  if (base + 2 < N) row_start[base + 2] = excl + v0 + v1;
  if (base + 3 < N) row_start[base + 3] = excl + v0 + v1 + v2;
}

__global__ __launch_bounds__(1024) void scan2_kernel(
    int* __restrict__ bsum, int* __restrict__ row_start, int nb, int E, int N) {
  __shared__ int s[1024];
  int t = threadIdx.x;
  s[t] = (t < nb) ? bsum[t] : 0;
  __syncthreads();
  for (int off = 1; off < 1024; off <<= 1) {
    int add = (t >= off) ? s[t - off] : 0;
    __syncthreads();
    s[t] += add;
    __syncthreads();
  }
  if (t < nb) bsum[t] = (t == 0) ? 0 : s[t - 1];
  if (t == 0) row_start[N] = E;
}

__global__ __launch_bounds__(256) void scan3_kernel(
    int* __restrict__ row_start, const int* __restrict__ bsum, int N) {
  int off = bsum[blockIdx.x];
  int base = blockIdx.x * 1024 + threadIdx.x * 4;
#pragma unroll
  for (int k = 0; k < 4; k++)
    if (base + k < N) row_start[base + k] += off;
}

__global__ __launch_bounds__(256) void fill_kernel(
    const int* __restrict__ ei, const int* __restrict__ row_start,
    int* __restrict__ cursor, int* __restrict__ csr_src, int E) {
  int e = blockIdx.x * 256 + threadIdx.x;
  if (e >= E) return;
  int s = ei[e];
  int d = ei[E + e];
  int pos = atomicAdd(&cursor[d], 1);
  csr_src[row_start[d] + pos] = s;
}

// ===========================================================================
// Weight transpose prep: wT[l][0][j][k] = Wrel[l][k][j], wT[l][1][j][k] = Wroot.
// Row j of wT = column j of W: per-lane contiguous for the mm kernel.
// ===========================================================================
__global__ __launch_bounds__(256) void transpose_w_kernel(
    const float* __restrict__ Wrel, const float* __restrict__ Wroot,
    float* __restrict__ wT) {
  int l = blockIdx.x;  // 0..2
  for (int idx = threadIdx.x; idx < D * D; idx += 256) {
    int k = idx >> 6, j = idx & 63;
    wT[l * 2 * D * D + j * D + k] = Wrel[l * D * D + k * D + j];
    wT[l * 2 * D * D + D * D + j * D + k] = Wroot[l * D * D + k * D + j];
  }
}

// ===========================================================================
// Gather: msg[i] = sum over in-edges of x[src]. One wave per node, lane=feat.
// ===========================================================================
__global__ __launch_bounds__(256) void gather_kernel(
    const float* __restrict__ x, const int* __restrict__ csr_src,
    const int* __restrict__ row_start, float* __restrict__ msg, int N) {
  int i = blockIdx.x * 4 + (threadIdx.x >> 6);
  int j = threadIdx.x & 63;
  if (i >= N) return;
  int e0 = row_start[i], e1 = row_start[i + 1];
  float acc = 0.f;
  int e = e0;
  for (; e + 3 < e1; e += 4) {
    int s0 = csr_src[e + 0], s1 = csr_src[e + 1];
    int s2 = csr_src[e + 2], s3 = csr_src[e + 3];
    acc += x[s0 * D + j];
    acc += x[s1 * D + j];
    acc += x[s2 * D + j];
    acc += x[s3 * D + j];
  }
  for (; e < e1; e++) acc += x[csr_src[e] * D + j];
  msg[i * D + j] = acc;
}

// ===========================================================================
// mm (col-per-lane): h = msg @ Wrel + brel + xin @ Wroot, IN PLACE over msg.
// Lane j = output column. Weight columns (128 floats) live in VGPRs; row data
// is wave-uniform -> scalar s_load; inner loop = v_fma(vgpr, sgpr) only.
// BN stats (per-col sum/sumsq) fused: lane j owns column j.
// ===========================================================================
__global__ __launch_bounds__(256) void mm_col_kernel(
    const float* __restrict__ msg, const float* __restrict__ xin,
    const float* __restrict__ wrelT, const float* __restrict__ wrootT,
    const float* __restrict__ brel, float* __restrict__ h,
    float* __restrict__ stats, int N, int nwaves) {
  int j = threadIdx.x & 63;
  // readfirstlane makes the wave id PROVABLY uniform -> row pointers uniform
  // -> compiler emits s_load for row data (the whole point of this kernel).
  int wid = __builtin_amdgcn_readfirstlane((int)(threadIdx.x >> 6));
  int gw = blockIdx.x * 4 + wid;

  float wr[D], wo[D];
  const float4* wrp = (const float4*)(wrelT + j * D);
  const float4* wop = (const float4*)(wrootT + j * D);
#pragma unroll
  for (int q = 0; q < 16; q++) {
    float4 a = wrp[q];
    float4 b = wop[q];
    wr[q * 4 + 0] = a.x; wr[q * 4 + 1] = a.y;
    wr[q * 4 + 2] = a.z; wr[q * 4 + 3] = a.w;
    wo[q * 4 + 0] = b.x; wo[q * 4 + 1] = b.y;
    wo[q * 4 + 2] = b.z; wo[q * 4 + 3] = b.w;
  }
  float bj = brel[j];
  float psum = 0.f, psq = 0.f;

  for (int i = gw; i < N; i += nwaves) {
    const float* mrow = msg + (size_t)i * D;   // wave-uniform -> s_load
    const float* xrow = xin + (size_t)i * D;   // wave-uniform -> s_load
    float a0 = 0.f, a1 = 0.f, a2 = 0.f, a3 = 0.f;
#pragma unroll
    for (int k = 0; k < D; k += 4) {
      a0 += mrow[k + 0] * wr[k + 0] + xrow[k + 0] * wo[k + 0];
      a1 += mrow[k + 1] * wr[k + 1] + xrow[k + 1] * wo[k + 1];
      a2 += mrow[k + 2] * wr[k + 2] + xrow[k + 2] * wo[k + 2];
      a3 += mrow[k + 3] * wr[k + 3] + xrow[k + 3] * wo[k + 3];
    }
    float hv = bj + ((a0 + a1) + (a2 + a3));
    h[(size_t)i * D + j] = hv;   // coalesced: lane j -> contiguous 256B
    psum += hv;
    psq += hv * hv;
  }
  atomicAdd(&stats[j], psum);
  atomicAdd(&stats[D + j], psq);
}

// ---------------------------------------------------------------------------
__global__ void bn_finalize_kernel(const float* __restrict__ stats,
                                   const float* __restrict__ gamma,
                                   const float* __restrict__ beta,
                                   float* __restrict__ scsh, float fN) {
  int j = threadIdx.x;  // 64 threads
  float mean = stats[j] / fN;
  float var = stats[D + j] / fN - mean * mean;
  float sc = gamma[j] * rsqrtf(var + BN_EPS);
  scsh[j] = sc;
  scsh[D + j] = beta[j] - mean * sc;
}

// ---------------------------------------------------------------------------
__global__ __launch_bounds__(256) void norm_relu_kernel(
    const float* __restrict__ h, const float* __restrict__ scsh,
    float* __restrict__ xout, int n) {
  int tid = blockIdx.x * 256 + threadIdx.x;
  int base = tid * 4;
  if (base >= n) return;
  int j = base & 63;
  float4 hv = *(const float4*)&h[base];
  float4 sc = *(const float4*)&scsh[j];
  float4 sh = *(const float4*)&scsh[D + j];
  float4 o;
  o.x = fmaxf(hv.x * sc.x + sh.x, 0.f);
  o.y = fmaxf(hv.y * sc.y + sh.y, 0.f);
  o.z = fmaxf(hv.z * sc.z + sh.z, 0.f);
  o.w = fmaxf(hv.w * sc.w + sh.w, 0.f);
  *(float4*)&xout[base] = o;
}

// ---------------------------------------------------------------------------
__global__ __launch_bounds__(256) void norm_relu_pool_kernel(
    const float* __restrict__ h, const float* __restrict__ scsh,
    const int* __restrict__ batch, float* __restrict__ pooled, int N) {
  int j = threadIdx.x & 63;
  int q = threadIdx.x >> 6;
  int i0 = blockIdx.x * 256;
  float sc = scsh[j], sh = scsh[D + j];
  int curg = -1;
  float acc = 0.f;
  for (int r = q; r < 256; r += 4) {
    int i = i0 + r;
    if (i >= N) break;
    int b = batch[i];
    float v = fmaxf(h[i * D + j] * sc + sh, 0.f);
    if (b != curg) {
      if (curg >= 0) atomicAdd(&pooled[curg * D + j], acc);
      curg = b;
      acc = v;
    } else {
      acc += v;
    }
  }
  if (curg >= 0) atomicAdd(&pooled[curg * D + j], acc);
}

// ---------------------------------------------------------------------------
__global__ void counts_kernel(const int* __restrict__ batch,
                              float* __restrict__ counts, int N) {
  int g = threadIdx.x;
  if (g >= NGRAPH) return;
  int lo = 0, hi = N;
  while (lo < hi) { int m = (lo + hi) >> 1; if (batch[m] < g) lo = m + 1; else hi = m; }
  int start = lo;
  lo = 0; hi = N;
  while (lo < hi) { int m = (lo + hi) >> 1; if (batch[m] <= g) lo = m + 1; else hi = m; }
  counts[g] = (float)(lo - start);
}

// ---------------------------------------------------------------------------
__global__ void cls_kernel(const float* __restrict__ pooled,
                           const float* __restrict__ counts,
                           const float* __restrict__ Wcls,
                           const float* __restrict__ bcls,
                           float* __restrict__ out) {
  int tid = blockIdx.x * blockDim.x + threadIdx.x;
  if (tid >= NGRAPH * NCLS) return;
  int g = tid / NCLS, c = tid % NCLS;
  float inv = 1.f / fmaxf(counts[g], 1.f);
  float acc = bcls[c];
#pragma unroll 8
  for (int k = 0; k < D; k++) acc += pooled[g * D + k] * inv * Wcls[k * NCLS + c];
  out[g * NCLS + c] = acc;
}

// ---------------------------------------------------------------------------
extern "C" void kernel_launch(void* const* d_in, const int* in_sizes, int n_in,
                              void* d_out, int out_size, void* d_ws, size_t ws_size,
                              hipStream_t stream) {
  const float* x      = (const float*)d_in[0];
  const int*   ei     = (const int*)d_in[1];
  const int*   batch  = (const int*)d_in[2];
  const float* W_rel  = (const float*)d_in[3];
  const float* b_rel  = (const float*)d_in[4];
  const float* W_root = (const float*)d_in[5];
  const float* gamma  = (const float*)d_in[6];
  const float* beta   = (const float*)d_in[7];
  const float* W_cls  = (const float*)d_in[8];
  const float* b_cls  = (const float*)d_in[9];
  float* out = (float*)d_out;

  int E = in_sizes[1] / 2;
  int N = in_sizes[2];
  size_t nd = (size_t)N * D;
  int nb = (N + 1023) / 1024;

  // Workspace layout.
  float* bufA   = (float*)d_ws;            // N*D: gather target / h in place
  float* bufB   = bufA + nd;               // N*D: normalized x ping-pong
  float* stats  = bufB + nd;               // 2*D
  float* scsh   = stats + 2 * D;           // 2*D
  float* pooled = scsh + 2 * D;            // NGRAPH*D
  float* counts = pooled + NGRAPH * D;     // NGRAPH
  float* wT     = counts + NGRAPH;         // 3 layers * 2 mats * 64*64
  int* deg       = (int*)(wT + 3 * 2 * D * D);
  int* cursor    = deg + N;
  int* row_start = cursor + N;             // N+1
  int* bsum      = row_start + N + 1;      // nb
  int* csr_src   = bsum + ((nb + 3) & ~3); // E

  // ---- Once-per-call prep ----
  hipMemsetAsync(deg, 0, 2 * N * sizeof(int), stream);  // deg + cursor
  hipMemsetAsync(pooled, 0, (NGRAPH * D + NGRAPH) * sizeof(float), stream);
  hist_kernel<<<(E + 255) / 256, 256, 0, stream>>>(ei, deg, E);
  scan1_kernel<<<nb, 256, 0, stream>>>(deg, row_start, bsum, N);
  scan2_kernel<<<1, 1024, 0, stream>>>(bsum, row_start, nb, E, N);
  scan3_kernel<<<nb, 256, 0, stream>>>(row_start, bsum, N);
  fill_kernel<<<(E + 255) / 256, 256, 0, stream>>>(ei, row_start, cursor, csr_src, E);
  transpose_w_kernel<<<3, 256, 0, stream>>>(W_rel, W_root, wT);

  // ---- Layers ----
  const int MM_BLOCKS = 1024;
  const int NWAVES = MM_BLOCKS * 4;
  const float* xin = x;
  for (int l = 0; l < 3; l++) {
    hipMemsetAsync(stats, 0, 2 * D * sizeof(float), stream);

    gather_kernel<<<(N + 3) / 4, 256, 0, stream>>>(xin, csr_src, row_start, bufA, N);

    const float* wrelT  = wT + l * 2 * D * D;
    const float* wrootT = wrelT + D * D;
    mm_col_kernel<<<MM_BLOCKS, 256, 0, stream>>>(
        bufA, xin, wrelT, wrootT, b_rel + l * D, bufA /* in place */,
        stats, N, NWAVES);

    bn_finalize_kernel<<<1, 64, 0, stream>>>(stats, gamma + l * D, beta + l * D,
                                             scsh, (float)N);

    if (l < 2) {
      int n = N * D;
      norm_relu_kernel<<<(n / 4 + 255) / 256, 256, 0, stream>>>(bufA, scsh, bufB, n);
      xin = bufB;
    } else {
      norm_relu_pool_kernel<<<(N + 255) / 256, 256, 0, stream>>>(bufA, scsh, batch,
                                                                 pooled, N);
    }
  }

  counts_kernel<<<1, 128, 0, stream>>>(batch, counts, N);
  cls_kernel<<<(NGRAPH * NCLS + 255) / 256, 256, 0, stream>>>(pooled, counts,
                                                              W_cls, b_cls, out);
}

// Round 5
// 849.889 us; speedup vs baseline: 1.9257x; 1.0612x over previous
//
#include <hip/hip_runtime.h>

#define D 64
#define NGRAPH 128
#define NCLS 10
#define BN_EPS 1e-5f

// Broadcast element k of a per-lane register across the wave (SGPR result).
__device__ __forceinline__ float lane_bcast(float v, int k) {
  return __builtin_bit_cast(float,
      __builtin_amdgcn_readlane(__builtin_bit_cast(int, v), k));
}

// ===========================================================================
// CSR construction (once per call; edge list identical across layers)
// ===========================================================================
__global__ __launch_bounds__(256) void hist_kernel(
    const int* __restrict__ ei, int* __restrict__ deg, int E) {
  int e = blockIdx.x * 256 + threadIdx.x;
  if (e >= E) return;
  atomicAdd(&deg[ei[E + e]], 1);
}

__global__ __launch_bounds__(256) void scan1_kernel(
    const int* __restrict__ deg, int* __restrict__ row_start,
    int* __restrict__ bsum, int N) {
  __shared__ int s[256];
  int t = threadIdx.x;
  int base = blockIdx.x * 1024 + t * 4;
  int v0 = (base + 0 < N) ? deg[base + 0] : 0;
  int v1 = (base + 1 < N) ? deg[base + 1] : 0;
  int v2 = (base + 2 < N) ? deg[base + 2] : 0;
  int v3 = (base + 3 < N) ? deg[base + 3] : 0;
  s[t] = v0 + v1 + v2 + v3;
  __syncthreads();
  for (int off = 1; off < 256; off <<= 1) {
    int add = (t >= off) ? s[t - off] : 0;
    __syncthreads();
    s[t] += add;
    __syncthreads();
  }
  int excl = (t == 0) ? 0 : s[t - 1];
  if (t == 255) bsum[blockIdx.x] = s[255];
  if (base + 0 < N) row_start[base + 0] = excl;
  if (base + 1 < N) row_start[base + 1] = excl + v0;
  if (base + 2 < N) row_start[base + 2] = excl + v0 + v1;
  if (base + 3 < N) row_start[base + 3] = excl + v0 + v1 + v2;
}

__global__ __launch_bounds__(1024) void scan2_kernel(
    int* __restrict__ bsum, int* __restrict__ row_start, int nb, int E, int N) {
  __shared__ int s[1024];
  int t = threadIdx.x;
  s[t] = (t < nb) ? bsum[t] : 0;
  __syncthreads();
  for (int off = 1; off < 1024; off <<= 1) {
    int add = (t >= off) ? s[t - off] : 0;
    __syncthreads();
    s[t] += add;
    __syncthreads();
  }
  if (t < nb) bsum[t] = (t == 0) ? 0 : s[t - 1];
  if (t == 0) row_start[N] = E;
}

__global__ __launch_bounds__(256) void scan3_kernel(
    int* __restrict__ row_start, const int* __restrict__ bsum, int N) {
  int off = bsum[blockIdx.x];
  int base = blockIdx.x * 1024 + threadIdx.x * 4;
#pragma unroll
  for (int k = 0; k < 4; k++)
    if (base + k < N) row_start[base + k] += off;
}

__global__ __launch_bounds__(256) void fill_kernel(
    const int* __restrict__ ei, const int* __restrict__ row_start,
    int* __restrict__ cursor, int* __restrict__ csr_src, int E) {
  int e = blockIdx.x * 256 + threadIdx.x;
  if (e >= E) return;
  int s = ei[e];
  int d = ei[E + e];
  int pos = atomicAdd(&cursor[d], 1);
  csr_src[row_start[d] + pos] = s;
}

// ===========================================================================
// Weight transpose prep: wT[l][0][j][k] = Wrel[l][k][j], wT[l][1][j][k] = Wroot.
// Row j of wT = column j of W: per-lane contiguous for the mm kernel.
// ===========================================================================
__global__ __launch_bounds__(256) void transpose_w_kernel(
    const float* __restrict__ Wrel, const float* __restrict__ Wroot,
    float* __restrict__ wT) {
  int l = blockIdx.x;  // 0..2
  for (int idx = threadIdx.x; idx < D * D; idx += 256) {
    int k = idx >> 6, j = idx & 63;
    wT[l * 2 * D * D + j * D + k] = Wrel[l * D * D + k * D + j];
    wT[l * 2 * D * D + D * D + j * D + k] = Wroot[l * D * D + k * D + j];
  }
}

// ===========================================================================
// Gather: msg[i] = sum over in-edges of x[src]. One wave per node, lane=feat.
// ===========================================================================
__global__ __launch_bounds__(256) void gather_kernel(
    const float* __restrict__ x, const int* __restrict__ csr_src,
    const int* __restrict__ row_start, float* __restrict__ msg, int N) {
  int i = blockIdx.x * 4 + (threadIdx.x >> 6);
  int j = threadIdx.x & 63;
  if (i >= N) return;
  int e0 = row_start[i], e1 = row_start[i + 1];
  float acc = 0.f;
  int e = e0;
  for (; e + 3 < e1; e += 4) {
    int s0 = csr_src[e + 0], s1 = csr_src[e + 1];
    int s2 = csr_src[e + 2], s3 = csr_src[e + 3];
    acc += x[s0 * D + j];
    acc += x[s1 * D + j];
    acc += x[s2 * D + j];
    acc += x[s3 * D + j];
  }
  for (; e < e1; e++) acc += x[csr_src[e] * D + j];
  msg[i * D + j] = acc;
}

// ===========================================================================
// mm (col-per-lane, readlane broadcast): h = msg@Wrel + brel + xin@Wroot,
// IN PLACE over msg. Lane j = output column; weight columns live in VGPRs
// (launch_bounds(256,1) lifts the VGPR cap so they actually stay resident).
// Row data: ONE coalesced vector load per operand per row (lane j holds
// row[j]); element k broadcast via v_readlane with compile-time index.
// Inner loop: 2 readlane + 2 FMA per k. Zero LDS, zero SMEM capacity issues.
// BN stats fused (lane j owns column j).
// ===========================================================================
__global__ __launch_bounds__(256, 1) void mm_col_kernel(
    const float* __restrict__ msg, const float* __restrict__ xin,
    const float* __restrict__ wrelT, const float* __restrict__ wrootT,
    const float* __restrict__ brel, float* __restrict__ h,
    float* __restrict__ stats, int N, int nwaves) {
  int j = threadIdx.x & 63;
  int gw = (blockIdx.x * 256 + threadIdx.x) >> 6;  // global wave id

  float wr[D], wo[D];
  const float4* wrp = (const float4*)(wrelT + j * D);
  const float4* wop = (const float4*)(wrootT + j * D);
#pragma unroll
  for (int q = 0; q < 16; q++) {
    float4 a = wrp[q];
    float4 b = wop[q];
    wr[q * 4 + 0] = a.x; wr[q * 4 + 1] = a.y;
    wr[q * 4 + 2] = a.z; wr[q * 4 + 3] = a.w;
    wo[q * 4 + 0] = b.x; wo[q * 4 + 1] = b.y;
    wo[q * 4 + 2] = b.z; wo[q * 4 + 3] = b.w;
  }
  float bj = brel[j];
  float psum = 0.f, psq = 0.f;

  for (int i = gw; i < N; i += nwaves) {
    float rm = msg[(size_t)i * D + j];   // coalesced 256B wave load
    float rx = xin[(size_t)i * D + j];
    float a0 = 0.f, a1 = 0.f, a2 = 0.f, a3 = 0.f;
#pragma unroll
    for (int k = 0; k < D; k += 4) {
      a0 += lane_bcast(rm, k + 0) * wr[k + 0] + lane_bcast(rx, k + 0) * wo[k + 0];
      a1 += lane_bcast(rm, k + 1) * wr[k + 1] + lane_bcast(rx, k + 1) * wo[k + 1];
      a2 += lane_bcast(rm, k + 2) * wr[k + 2] + lane_bcast(rx, k + 2) * wo[k + 2];
      a3 += lane_bcast(rm, k + 3) * wr[k + 3] + lane_bcast(rx, k + 3) * wo[k + 3];
    }
    float hv = bj + ((a0 + a1) + (a2 + a3));
    h[(size_t)i * D + j] = hv;   // coalesced 256B wave store
    psum += hv;
    psq += hv * hv;
  }
  atomicAdd(&stats[j], psum);
  atomicAdd(&stats[D + j], psq);
}

// ---------------------------------------------------------------------------
__global__ void bn_finalize_kernel(const float* __restrict__ stats,
                                   const float* __restrict__ gamma,
                                   const float* __restrict__ beta,
                                   float* __restrict__ scsh, float fN) {
  int j = threadIdx.x;  // 64 threads
  float mean = stats[j] / fN;
  float var = stats[D + j] / fN - mean * mean;
  float sc = gamma[j] * rsqrtf(var + BN_EPS);
  scsh[j] = sc;
  scsh[D + j] = beta[j] - mean * sc;
}

// ---------------------------------------------------------------------------
__global__ __launch_bounds__(256) void norm_relu_kernel(
    const float* __restrict__ h, const float* __restrict__ scsh,
    float* __restrict__ xout, int n) {
  int tid = blockIdx.x * 256 + threadIdx.x;
  int base = tid * 4;
  if (base >= n) return;
  int j = base & 63;
  float4 hv = *(const float4*)&h[base];
  float4 sc = *(const float4*)&scsh[j];
  float4 sh = *(const float4*)&scsh[D + j];
  float4 o;
  o.x = fmaxf(hv.x * sc.x + sh.x, 0.f);
  o.y = fmaxf(hv.y * sc.y + sh.y, 0.f);
  o.z = fmaxf(hv.z * sc.z + sh.z, 0.f);
  o.w = fmaxf(hv.w * sc.w + sh.w, 0.f);
  *(float4*)&xout[base] = o;
}

// ---------------------------------------------------------------------------
__global__ __launch_bounds__(256) void norm_relu_pool_kernel(
    const float* __restrict__ h, const float* __restrict__ scsh,
    const int* __restrict__ batch, float* __restrict__ pooled, int N) {
  int j = threadIdx.x & 63;
  int q = threadIdx.x >> 6;
  int i0 = blockIdx.x * 256;
  float sc = scsh[j], sh = scsh[D + j];
  int curg = -1;
  float acc = 0.f;
  for (int r = q; r < 256; r += 4) {
    int i = i0 + r;
    if (i >= N) break;
    int b = batch[i];
    float v = fmaxf(h[i * D + j] * sc + sh, 0.f);
    if (b != curg) {
      if (curg >= 0) atomicAdd(&pooled[curg * D + j], acc);
      curg = b;
      acc = v;
    } else {
      acc += v;
    }
  }
  if (curg >= 0) atomicAdd(&pooled[curg * D + j], acc);
}

// ---------------------------------------------------------------------------
__global__ void counts_kernel(const int* __restrict__ batch,
                              float* __restrict__ counts, int N) {
  int g = threadIdx.x;
  if (g >= NGRAPH) return;
  int lo = 0, hi = N;
  while (lo < hi) { int m = (lo + hi) >> 1; if (batch[m] < g) lo = m + 1; else hi = m; }
  int start = lo;
  lo = 0; hi = N;
  while (lo < hi) { int m = (lo + hi) >> 1; if (batch[m] <= g) lo = m + 1; else hi = m; }
  counts[g] = (float)(lo - start);
}

// ---------------------------------------------------------------------------
__global__ void cls_kernel(const float* __restrict__ pooled,
                           const float* __restrict__ counts,
                           const float* __restrict__ Wcls,
                           const float* __restrict__ bcls,
                           float* __restrict__ out) {
  int tid = blockIdx.x * blockDim.x + threadIdx.x;
  if (tid >= NGRAPH * NCLS) return;
  int g = tid / NCLS, c = tid % NCLS;
  float inv = 1.f / fmaxf(counts[g], 1.f);
  float acc = bcls[c];
#pragma unroll 8
  for (int k = 0; k < D; k++) acc += pooled[g * D + k] * inv * Wcls[k * NCLS + c];
  out[g * NCLS + c] = acc;
}

// ---------------------------------------------------------------------------
extern "C" void kernel_launch(void* const* d_in, const int* in_sizes, int n_in,
                              void* d_out, int out_size, void* d_ws, size_t ws_size,
                              hipStream_t stream) {
  const float* x      = (const float*)d_in[0];
  const int*   ei     = (const int*)d_in[1];
  const int*   batch  = (const int*)d_in[2];
  const float* W_rel  = (const float*)d_in[3];
  const float* b_rel  = (const float*)d_in[4];
  const float* W_root = (const float*)d_in[5];
  const float* gamma  = (const float*)d_in[6];
  const float* beta   = (const float*)d_in[7];
  const float* W_cls  = (const float*)d_in[8];
  const float* b_cls  = (const float*)d_in[9];
  float* out = (float*)d_out;

  int E = in_sizes[1] / 2;
  int N = in_sizes[2];
  size_t nd = (size_t)N * D;
  int nb = (N + 1023) / 1024;

  // Workspace layout.
  float* bufA   = (float*)d_ws;            // N*D: gather target / h in place
  float* bufB   = bufA + nd;               // N*D: normalized x ping-pong
  float* stats  = bufB + nd;               // 2*D
  float* scsh   = stats + 2 * D;           // 2*D
  float* pooled = scsh + 2 * D;            // NGRAPH*D
  float* counts = pooled + NGRAPH * D;     // NGRAPH
  float* wT     = counts + NGRAPH;         // 3 layers * 2 mats * 64*64
  int* deg       = (int*)(wT + 3 * 2 * D * D);
  int* cursor    = deg + N;
  int* row_start = cursor + N;             // N+1
  int* bsum      = row_start + N + 1;      // nb
  int* csr_src   = bsum + ((nb + 3) & ~3); // E

  // ---- Once-per-call prep ----
  hipMemsetAsync(deg, 0, 2 * N * sizeof(int), stream);  // deg + cursor
  hipMemsetAsync(pooled, 0, (NGRAPH * D + NGRAPH) * sizeof(float), stream);
  hist_kernel<<<(E + 255) / 256, 256, 0, stream>>>(ei, deg, E);
  scan1_kernel<<<nb, 256, 0, stream>>>(deg, row_start, bsum, N);
  scan2_kernel<<<1, 1024, 0, stream>>>(bsum, row_start, nb, E, N);
  scan3_kernel<<<nb, 256, 0, stream>>>(row_start, bsum, N);
  fill_kernel<<<(E + 255) / 256, 256, 0, stream>>>(ei, row_start, cursor, csr_src, E);
  transpose_w_kernel<<<3, 256, 0, stream>>>(W_rel, W_root, wT);

  // ---- Layers ----
  const int MM_BLOCKS = 1024;
  const int NWAVES = MM_BLOCKS * 4;
  const float* xin = x;
  for (int l = 0; l < 3; l++) {
    hipMemsetAsync(stats, 0, 2 * D * sizeof(float), stream);

    gather_kernel<<<(N + 3) / 4, 256, 0, stream>>>(xin, csr_src, row_start, bufA, N);

    const float* wrelT  = wT + l * 2 * D * D;
    const float* wrootT = wrelT + D * D;
    mm_col_kernel<<<MM_BLOCKS, 256, 0, stream>>>(
        bufA, xin, wrelT, wrootT, b_rel + l * D, bufA /* in place */,
        stats, N, NWAVES);

    bn_finalize_kernel<<<1, 64, 0, stream>>>(stats, gamma + l * D, beta + l * D,
                                             scsh, (float)N);

    if (l < 2) {
      int n = N * D;
      norm_relu_kernel<<<(n / 4 + 255) / 256, 256, 0, stream>>>(bufA, scsh, bufB, n);
      xin = bufB;
    } else {
      norm_relu_pool_kernel<<<(N + 255) / 256, 256, 0, stream>>>(bufA, scsh, batch,
                                                                 pooled, N);
    }
  }

  counts_kernel<<<1, 128, 0, stream>>>(batch, counts, N);
  cls_kernel<<<(NGRAPH * NCLS + 255) / 256, 256, 0, stream>>>(pooled, counts,
                                                              W_cls, b_cls, out);
}

// Round 6
// 847.809 us; speedup vs baseline: 1.9304x; 1.0025x over previous
//
#include <hip/hip_runtime.h>

#define D 64
#define NGRAPH 128
#define NCLS 10
#define BN_EPS 1e-5f

// Broadcast element k of a per-lane register across the wave (SGPR result).
__device__ __forceinline__ float lane_bcast(float v, int k) {
  return __builtin_bit_cast(float,
      __builtin_amdgcn_readlane(__builtin_bit_cast(int, v), k));
}

// ===========================================================================
// CSR construction (once per call; edge list identical across layers)
// ===========================================================================
__global__ __launch_bounds__(256) void hist_kernel(
    const int* __restrict__ ei, int* __restrict__ deg, int E) {
  int e = blockIdx.x * 256 + threadIdx.x;
  if (e >= E) return;
  atomicAdd(&deg[ei[E + e]], 1);
}

__global__ __launch_bounds__(256) void scan1_kernel(
    const int* __restrict__ deg, int* __restrict__ row_start,
    int* __restrict__ bsum, int N) {
  __shared__ int s[256];
  int t = threadIdx.x;
  int base = blockIdx.x * 1024 + t * 4;
  int v0 = (base + 0 < N) ? deg[base + 0] : 0;
  int v1 = (base + 1 < N) ? deg[base + 1] : 0;
  int v2 = (base + 2 < N) ? deg[base + 2] : 0;
  int v3 = (base + 3 < N) ? deg[base + 3] : 0;
  s[t] = v0 + v1 + v2 + v3;
  __syncthreads();
  for (int off = 1; off < 256; off <<= 1) {
    int add = (t >= off) ? s[t - off] : 0;
    __syncthreads();
    s[t] += add;
    __syncthreads();
  }
  int excl = (t == 0) ? 0 : s[t - 1];
  if (t == 255) bsum[blockIdx.x] = s[255];
  if (base + 0 < N) row_start[base + 0] = excl;
  if (base + 1 < N) row_start[base + 1] = excl + v0;
  if (base + 2 < N) row_start[base + 2] = excl + v0 + v1;
  if (base + 3 < N) row_start[base + 3] = excl + v0 + v1 + v2;
}

__global__ __launch_bounds__(1024) void scan2_kernel(
    int* __restrict__ bsum, int* __restrict__ row_start, int nb, int E, int N) {
  __shared__ int s[1024];
  int t = threadIdx.x;
  s[t] = (t < nb) ? bsum[t] : 0;
  __syncthreads();
  for (int off = 1; off < 1024; off <<= 1) {
    int add = (t >= off) ? s[t - off] : 0;
    __syncthreads();
    s[t] += add;
    __syncthreads();
  }
  if (t < nb) bsum[t] = (t == 0) ? 0 : s[t - 1];
  if (t == 0) row_start[N] = E;
}

__global__ __launch_bounds__(256) void scan3_kernel(
    int* __restrict__ row_start, const int* __restrict__ bsum, int N) {
  int off = bsum[blockIdx.x];
  int base = blockIdx.x * 1024 + threadIdx.x * 4;
#pragma unroll
  for (int k = 0; k < 4; k++)
    if (base + k < N) row_start[base + k] += off;
}

__global__ __launch_bounds__(256) void fill_kernel(
    const int* __restrict__ ei, const int* __restrict__ row_start,
    int* __restrict__ cursor, int* __restrict__ csr_src, int E) {
  int e = blockIdx.x * 256 + threadIdx.x;
  if (e >= E) return;
  int s = ei[e];
  int d = ei[E + e];
  int pos = atomicAdd(&cursor[d], 1);
  csr_src[row_start[d] + pos] = s;
}

// ===========================================================================
// Weight transpose prep: wT[l][0][j][k] = Wrel[l][k][j], wT[l][1][j][k] = Wroot.
// ===========================================================================
__global__ __launch_bounds__(256) void transpose_w_kernel(
    const float* __restrict__ Wrel, const float* __restrict__ Wroot,
    float* __restrict__ wT) {
  int l = blockIdx.x;  // 0..2
  for (int idx = threadIdx.x; idx < D * D; idx += 256) {
    int k = idx >> 6, j = idx & 63;
    wT[l * 2 * D * D + j * D + k] = Wrel[l * D * D + k * D + j];
    wT[l * 2 * D * D + D * D + j * D + k] = Wroot[l * D * D + k * D + j];
  }
}

// ===========================================================================
// Gather: msg[i] = sum over in-edges of x[src]. One wave per node, lane=feat.
// ===========================================================================
__global__ __launch_bounds__(256) void gather_kernel(
    const float* __restrict__ x, const int* __restrict__ csr_src,
    const int* __restrict__ row_start, float* __restrict__ msg, int N) {
  int i = blockIdx.x * 4 + (threadIdx.x >> 6);
  int j = threadIdx.x & 63;
  if (i >= N) return;
  int e0 = row_start[i], e1 = row_start[i + 1];
  float acc = 0.f;
  int e = e0;
  for (; e + 3 < e1; e += 4) {
    int s0 = csr_src[e + 0], s1 = csr_src[e + 1];
    int s2 = csr_src[e + 2], s3 = csr_src[e + 3];
    acc += x[s0 * D + j];
    acc += x[s1 * D + j];
    acc += x[s2 * D + j];
    acc += x[s3 * D + j];
  }
  for (; e < e1; e++) acc += x[csr_src[e] * D + j];
  msg[i * D + j] = acc;
}

// ===========================================================================
// mm (col-per-lane, readlane broadcast, ASM-PINNED weights):
// h = msg@Wrel + brel + xin@Wroot, IN PLACE over msg.
// R5 failure mode: compiler rematerialized the weight loads inside the row
// loop (VGPR_Count=76 < 128 needed) -> 3.2 GB/layer of L2 weight re-reads.
// Fix: empty asm "+v" constraints make each weight an opaque SSA value that
// CANNOT be re-derived from memory -> forced VGPR residency.
// ===========================================================================
__global__ __launch_bounds__(256, 1) void mm_col_kernel(
    const float* __restrict__ msg, const float* __restrict__ xin,
    const float* __restrict__ wrelT, const float* __restrict__ wrootT,
    const float* __restrict__ brel, float* __restrict__ h,
    float* __restrict__ stats, int N, int nwaves) {
  int j = threadIdx.x & 63;
  int gw = (blockIdx.x * 256 + threadIdx.x) >> 6;  // global wave id

  float wr[D], wo[D];
  const float4* wrp = (const float4*)(wrelT + j * D);
  const float4* wop = (const float4*)(wrootT + j * D);
#pragma unroll
  for (int q = 0; q < 16; q++) {
    float4 a = wrp[q];
    float4 b = wop[q];
    wr[q * 4 + 0] = a.x; wr[q * 4 + 1] = a.y;
    wr[q * 4 + 2] = a.z; wr[q * 4 + 3] = a.w;
    wo[q * 4 + 0] = b.x; wo[q * 4 + 1] = b.y;
    wo[q * 4 + 2] = b.z; wo[q * 4 + 3] = b.w;
  }
  // Pin every weight into a VGPR: opaque to rematerialization.
#pragma unroll
  for (int k = 0; k < D; k++) {
    asm volatile("" : "+v"(wr[k]));
    asm volatile("" : "+v"(wo[k]));
  }
  float bj = brel[j];
  float psum = 0.f, psq = 0.f;

  for (int i = gw; i < N; i += nwaves) {
    float rm = msg[(size_t)i * D + j];   // coalesced 256B wave load
    float rx = xin[(size_t)i * D + j];
    float a0 = 0.f, a1 = 0.f, a2 = 0.f, a3 = 0.f;
#pragma unroll
    for (int k = 0; k < D; k += 4) {
      a0 += lane_bcast(rm, k + 0) * wr[k + 0] + lane_bcast(rx, k + 0) * wo[k + 0];
      a1 += lane_bcast(rm, k + 1) * wr[k + 1] + lane_bcast(rx, k + 1) * wo[k + 1];
      a2 += lane_bcast(rm, k + 2) * wr[k + 2] + lane_bcast(rx, k + 2) * wo[k + 2];
      a3 += lane_bcast(rm, k + 3) * wr[k + 3] + lane_bcast(rx, k + 3) * wo[k + 3];
    }
    float hv = bj + ((a0 + a1) + (a2 + a3));
    h[(size_t)i * D + j] = hv;   // coalesced 256B wave store
    psum += hv;
    psq += hv * hv;
  }
  atomicAdd(&stats[j], psum);
  atomicAdd(&stats[D + j], psq);
}

// ---------------------------------------------------------------------------
__global__ void bn_finalize_kernel(const float* __restrict__ stats,
                                   const float* __restrict__ gamma,
                                   const float* __restrict__ beta,
                                   float* __restrict__ scsh, float fN) {
  int j = threadIdx.x;  // 64 threads
  float mean = stats[j] / fN;
  float var = stats[D + j] / fN - mean * mean;
  float sc = gamma[j] * rsqrtf(var + BN_EPS);
  scsh[j] = sc;
  scsh[D + j] = beta[j] - mean * sc;
}

// ---------------------------------------------------------------------------
__global__ __launch_bounds__(256) void norm_relu_kernel(
    const float* __restrict__ h, const float* __restrict__ scsh,
    float* __restrict__ xout, int n) {
  int tid = blockIdx.x * 256 + threadIdx.x;
  int base = tid * 4;
  if (base >= n) return;
  int j = base & 63;
  float4 hv = *(const float4*)&h[base];
  float4 sc = *(const float4*)&scsh[j];
  float4 sh = *(const float4*)&scsh[D + j];
  float4 o;
  o.x = fmaxf(hv.x * sc.x + sh.x, 0.f);
  o.y = fmaxf(hv.y * sc.y + sh.y, 0.f);
  o.z = fmaxf(hv.z * sc.z + sh.z, 0.f);
  o.w = fmaxf(hv.w * sc.w + sh.w, 0.f);
  *(float4*)&xout[base] = o;
}

// ---------------------------------------------------------------------------
__global__ __launch_bounds__(256) void norm_relu_pool_kernel(
    const float* __restrict__ h, const float* __restrict__ scsh,
    const int* __restrict__ batch, float* __restrict__ pooled, int N) {
  int j = threadIdx.x & 63;
  int q = threadIdx.x >> 6;
  int i0 = blockIdx.x * 256;
  float sc = scsh[j], sh = scsh[D + j];
  int curg = -1;
  float acc = 0.f;
  for (int r = q; r < 256; r += 4) {
    int i = i0 + r;
    if (i >= N) break;
    int b = batch[i];
    float v = fmaxf(h[i * D + j] * sc + sh, 0.f);
    if (b != curg) {
      if (curg >= 0) atomicAdd(&pooled[curg * D + j], acc);
      curg = b;
      acc = v;
    } else {
      acc += v;
    }
  }
  if (curg >= 0) atomicAdd(&pooled[curg * D + j], acc);
}

// ---------------------------------------------------------------------------
__global__ void counts_kernel(const int* __restrict__ batch,
                              float* __restrict__ counts, int N) {
  int g = threadIdx.x;
  if (g >= NGRAPH) return;
  int lo = 0, hi = N;
  while (lo < hi) { int m = (lo + hi) >> 1; if (batch[m] < g) lo = m + 1; else hi = m; }
  int start = lo;
  lo = 0; hi = N;
  while (lo < hi) { int m = (lo + hi) >> 1; if (batch[m] <= g) lo = m + 1; else hi = m; }
  counts[g] = (float)(lo - start);
}

// ---------------------------------------------------------------------------
__global__ void cls_kernel(const float* __restrict__ pooled,
                           const float* __restrict__ counts,
                           const float* __restrict__ Wcls,
                           const float* __restrict__ bcls,
                           float* __restrict__ out) {
  int tid = blockIdx.x * blockDim.x + threadIdx.x;
  if (tid >= NGRAPH * NCLS) return;
  int g = tid / NCLS, c = tid % NCLS;
  float inv = 1.f / fmaxf(counts[g], 1.f);
  float acc = bcls[c];
#pragma unroll 8
  for (int k = 0; k < D; k++) acc += pooled[g * D + k] * inv * Wcls[k * NCLS + c];
  out[g * NCLS + c] = acc;
}

// ---------------------------------------------------------------------------
extern "C" void kernel_launch(void* const* d_in, const int* in_sizes, int n_in,
                              void* d_out, int out_size, void* d_ws, size_t ws_size,
                              hipStream_t stream) {
  const float* x      = (const float*)d_in[0];
  const int*   ei     = (const int*)d_in[1];
  const int*   batch  = (const int*)d_in[2];
  const float* W_rel  = (const float*)d_in[3];
  const float* b_rel  = (const float*)d_in[4];
  const float* W_root = (const float*)d_in[5];
  const float* gamma  = (const float*)d_in[6];
  const float* beta   = (const float*)d_in[7];
  const float* W_cls  = (const float*)d_in[8];
  const float* b_cls  = (const float*)d_in[9];
  float* out = (float*)d_out;

  int E = in_sizes[1] / 2;
  int N = in_sizes[2];
  size_t nd = (size_t)N * D;
  int nb = (N + 1023) / 1024;

  // Workspace layout.
  float* bufA   = (float*)d_ws;            // N*D: gather target / h in place
  float* bufB   = bufA + nd;               // N*D: normalized x ping-pong
  float* stats  = bufB + nd;               // 2*D
  float* scsh   = stats + 2 * D;           // 2*D
  float* pooled = scsh + 2 * D;            // NGRAPH*D
  float* counts = pooled + NGRAPH * D;     // NGRAPH
  float* wT     = counts + NGRAPH;         // 3 layers * 2 mats * 64*64
  int* deg       = (int*)(wT + 3 * 2 * D * D);
  int* cursor    = deg + N;
  int* row_start = cursor + N;             // N+1
  int* bsum      = row_start + N + 1;      // nb
  int* csr_src   = bsum + ((nb + 3) & ~3); // E

  // ---- Once-per-call prep ----
  hipMemsetAsync(deg, 0, 2 * N * sizeof(int), stream);  // deg + cursor
  hipMemsetAsync(pooled, 0, (NGRAPH * D + NGRAPH) * sizeof(float), stream);
  hist_kernel<<<(E + 255) / 256, 256, 0, stream>>>(ei, deg, E);
  scan1_kernel<<<nb, 256, 0, stream>>>(deg, row_start, bsum, N);
  scan2_kernel<<<1, 1024, 0, stream>>>(bsum, row_start, nb, E, N);
  scan3_kernel<<<nb, 256, 0, stream>>>(row_start, bsum, N);
  fill_kernel<<<(E + 255) / 256, 256, 0, stream>>>(ei, row_start, cursor, csr_src, E);
  transpose_w_kernel<<<3, 256, 0, stream>>>(W_rel, W_root, wT);

  // ---- Layers ----
  const int MM_BLOCKS = 1024;
  const int NWAVES = MM_BLOCKS * 4;
  const float* xin = x;
  for (int l = 0; l < 3; l++) {
    hipMemsetAsync(stats, 0, 2 * D * sizeof(float), stream);

    gather_kernel<<<(N + 3) / 4, 256, 0, stream>>>(xin, csr_src, row_start, bufA, N);

    const float* wrelT  = wT + l * 2 * D * D;
    const float* wrootT = wrelT + D * D;
    mm_col_kernel<<<MM_BLOCKS, 256, 0, stream>>>(
        bufA, xin, wrelT, wrootT, b_rel + l * D, bufA /* in place */,
        stats, N, NWAVES);

    bn_finalize_kernel<<<1, 64, 0, stream>>>(stats, gamma + l * D, beta + l * D,
                                             scsh, (float)N);

    if (l < 2) {
      int n = N * D;
      norm_relu_kernel<<<(n / 4 + 255) / 256, 256, 0, stream>>>(bufA, scsh, bufB, n);
      xin = bufB;
    } else {
      norm_relu_pool_kernel<<<(N + 255) / 256, 256, 0, stream>>>(bufA, scsh, batch,
                                                                 pooled, N);
    }
  }

  counts_kernel<<<1, 128, 0, stream>>>(batch, counts, N);
  cls_kernel<<<(NGRAPH * NCLS + 255) / 256, 256, 0, stream>>>(pooled, counts,
                                                              W_cls, b_cls, out);
}

// Round 7
// 535.379 us; speedup vs baseline: 3.0570x; 1.5836x over previous
//
#include <hip/hip_runtime.h>

#define D 64
#define NGRAPH 128
#define NCLS 10
#define BN_EPS 1e-5f

typedef __attribute__((ext_vector_type(8))) __bf16 bf16x8;
typedef __attribute__((ext_vector_type(4))) float floatx4;

union BF8 { bf16x8 v; ushort u[8]; };

// Split 8 fp32 into bf16 hi (truncation) + bf16 lo (residual, truncated).
// x = hi + lo with relative error ~2^-17.
__device__ __forceinline__ void split8(float4 a, float4 b,
                                       bf16x8* hi, bf16x8* lo) {
  float f[8] = {a.x, a.y, a.z, a.w, b.x, b.y, b.z, b.w};
  BF8 H, L;
#pragma unroll
  for (int t = 0; t < 8; t++) {
    unsigned u = __float_as_uint(f[t]);
    H.u[t] = (ushort)(u >> 16);
    float hf = __uint_as_float(u & 0xFFFF0000u);
    float lf = f[t] - hf;
    L.u[t] = (ushort)(__float_as_uint(lf) >> 16);
  }
  *hi = H.v;
  *lo = L.v;
}

// ===========================================================================
// CSR construction (once per call; edge list identical across layers)
// ===========================================================================
__global__ __launch_bounds__(256) void hist_kernel(
    const int* __restrict__ ei, int* __restrict__ deg, int E) {
  int e = blockIdx.x * 256 + threadIdx.x;
  if (e >= E) return;
  atomicAdd(&deg[ei[E + e]], 1);
}

__global__ __launch_bounds__(256) void scan1_kernel(
    const int* __restrict__ deg, int* __restrict__ row_start,
    int* __restrict__ bsum, int N) {
  __shared__ int s[256];
  int t = threadIdx.x;
  int base = blockIdx.x * 1024 + t * 4;
  int v0 = (base + 0 < N) ? deg[base + 0] : 0;
  int v1 = (base + 1 < N) ? deg[base + 1] : 0;
  int v2 = (base + 2 < N) ? deg[base + 2] : 0;
  int v3 = (base + 3 < N) ? deg[base + 3] : 0;
  s[t] = v0 + v1 + v2 + v3;
  __syncthreads();
  for (int off = 1; off < 256; off <<= 1) {
    int add = (t >= off) ? s[t - off] : 0;
    __syncthreads();
    s[t] += add;
    __syncthreads();
  }
  int excl = (t == 0) ? 0 : s[t - 1];
  if (t == 255) bsum[blockIdx.x] = s[255];
  if (base + 0 < N) row_start[base + 0] = excl;
  if (base + 1 < N) row_start[base + 1] = excl + v0;
  if (base + 2 < N) row_start[base + 2] = excl + v0 + v1;
  if (base + 3 < N) row_start[base + 3] = excl + v0 + v1 + v2;
}

__global__ __launch_bounds__(1024) void scan2_kernel(
    int* __restrict__ bsum, int* __restrict__ row_start, int nb, int E, int N) {
  __shared__ int s[1024];
  int t = threadIdx.x;
  s[t] = (t < nb) ? bsum[t] : 0;
  __syncthreads();
  for (int off = 1; off < 1024; off <<= 1) {
    int add = (t >= off) ? s[t - off] : 0;
    __syncthreads();
    s[t] += add;
    __syncthreads();
  }
  if (t < nb) bsum[t] = (t == 0) ? 0 : s[t - 1];
  if (t == 0) row_start[N] = E;
}

__global__ __launch_bounds__(256) void scan3_kernel(
    int* __restrict__ row_start, const int* __restrict__ bsum, int N) {
  int off = bsum[blockIdx.x];
  int base = blockIdx.x * 1024 + threadIdx.x * 4;
#pragma unroll
  for (int k = 0; k < 4; k++)
    if (base + k < N) row_start[base + k] += off;
}

__global__ __launch_bounds__(256) void fill_kernel(
    const int* __restrict__ ei, const int* __restrict__ row_start,
    int* __restrict__ cursor, int* __restrict__ csr_src, int E) {
  int e = blockIdx.x * 256 + threadIdx.x;
  if (e >= E) return;
  int s = ei[e];
  int d = ei[E + e];
  int pos = atomicAdd(&cursor[d], 1);
  csr_src[row_start[d] + pos] = s;
}

// ===========================================================================
// Weight split+swizzle prep (once): stacked W = [Wrel; Wroot] (128x64) per
// layer, split into bf16 hi/lo, stored frag-major so the mm kernel loads one
// dwordx4 per fragment. Frag (kt,nt,s): lane (quad,c) holds
// W[k=kt*32+quad*8+j][n=nt*16+c], j=0..7.
// ===========================================================================
__global__ __launch_bounds__(256) void wsplit_kernel(
    const float* __restrict__ Wrel, const float* __restrict__ Wroot,
    ushort* __restrict__ wfrag) {
  int l = blockIdx.x;  // 0..2
  const float* Wr = Wrel + l * 4096;
  const float* Wo = Wroot + l * 4096;
  ushort* base = wfrag + l * 16384;
  for (int slot = threadIdx.x; slot < 1024; slot += 256) {
    int kt = slot >> 8, nt = (slot >> 6) & 3, lane = slot & 63;
    int quad = lane >> 4, c = lane & 15;
    ushort* ph = base + (((kt * 4 + nt) * 2 + 0) * 64 + lane) * 8;
    ushort* pl = base + (((kt * 4 + nt) * 2 + 1) * 64 + lane) * 8;
#pragma unroll
    for (int j = 0; j < 8; j++) {
      int k = kt * 32 + quad * 8 + j;
      int n = nt * 16 + c;
      float w = (k < 64) ? Wr[k * 64 + n] : Wo[(k - 64) * 64 + n];
      unsigned u = __float_as_uint(w);
      ph[j] = (ushort)(u >> 16);
      float lf = w - __uint_as_float(u & 0xFFFF0000u);
      pl[j] = (ushort)(__float_as_uint(lf) >> 16);
    }
  }
}

// ===========================================================================
// Gather: msg[i] = sum over in-edges of x[src]. One wave per node, lane=feat.
// ===========================================================================
__global__ __launch_bounds__(256) void gather_kernel(
    const float* __restrict__ x, const int* __restrict__ csr_src,
    const int* __restrict__ row_start, float* __restrict__ msg, int N) {
  int i = blockIdx.x * 4 + (threadIdx.x >> 6);
  int j = threadIdx.x & 63;
  if (i >= N) return;
  int e0 = row_start[i], e1 = row_start[i + 1];
  float acc = 0.f;
  int e = e0;
  for (; e + 3 < e1; e += 4) {
    int s0 = csr_src[e + 0], s1 = csr_src[e + 1];
    int s2 = csr_src[e + 2], s3 = csr_src[e + 3];
    acc += x[s0 * D + j];
    acc += x[s1 * D + j];
    acc += x[s2 * D + j];
    acc += x[s3 * D + j];
  }
  for (; e < e1; e++) acc += x[csr_src[e] * D + j];
  msg[i * D + j] = acc;
}

// ===========================================================================
// mm via MFMA split-bf16: h = [msg|x] @ [Wrel;Wroot] + brel, IN PLACE over
// msg. One wave per 16-row tile (grid-stride). A-frags built directly from
// global fp32 (lane loads exactly its 8 elements per ktile, converts in
// regs). B-frags resident in VGPRs (32 x short8). 48 MFMAs per tile:
// 4 ntiles x 4 ktiles x {hi*hi, hi*lo, lo*hi}. BN stats fused.
// C layout (verified, docs m89/m91): col = lane&15, row = quad*4 + reg.
// ===========================================================================
__global__ __launch_bounds__(256, 1) void mm_mfma_kernel(
    const float* __restrict__ msg, const float* __restrict__ xin,
    const ushort* __restrict__ wfrag, const float* __restrict__ brel,
    float* __restrict__ h, float* __restrict__ stats,
    int N, int ntiles, int nwaves) {
  __shared__ float ssum[4][64];
  __shared__ float ssq[4][64];
  int tid = threadIdx.x;
  int lane = tid & 63;
  int wvid = tid >> 6;
  int wv = (blockIdx.x * 256 + tid) >> 6;
  int quad = lane >> 4;
  int lo4 = lane & 15;

  // B fragments: 32 x 16B per lane, kept in VGPRs.
  bf16x8 bf[4][4][2];
#pragma unroll
  for (int kt = 0; kt < 4; kt++)
#pragma unroll
    for (int nt = 0; nt < 4; nt++)
#pragma unroll
      for (int s = 0; s < 2; s++)
        bf[kt][nt][s] =
            *(const bf16x8*)(wfrag + (((kt * 4 + nt) * 2 + s) * 64 + lane) * 8);

  float bias[4];
#pragma unroll
  for (int nt = 0; nt < 4; nt++) bias[nt] = brel[nt * 16 + lo4];

  float psum[4] = {0.f, 0.f, 0.f, 0.f};
  float psq[4] = {0.f, 0.f, 0.f, 0.f};

  for (int t = wv; t < ntiles; t += nwaves) {
    int i0 = t * 16;
    int row = i0 + lo4;
    if (row >= N) row = N - 1;
    // A fragments: lane (quad,m=lo4) loads A[m][k=quad*8..+7] per ktile.
    bf16x8 ahi[4], alo[4];
#pragma unroll
    for (int kt = 0; kt < 4; kt++) {
      const float* base = (kt < 2) ? msg : xin;
      const float* p = base + (size_t)row * D + (kt & 1) * 32 + quad * 8;
      float4 a = *(const float4*)p;
      float4 b = *(const float4*)(p + 4);
      split8(a, b, &ahi[kt], &alo[kt]);
    }
#pragma unroll
    for (int nt = 0; nt < 4; nt++) {
      floatx4 acc = {bias[nt], bias[nt], bias[nt], bias[nt]};
#pragma unroll
      for (int kt = 0; kt < 4; kt++) {
        acc = __builtin_amdgcn_mfma_f32_16x16x32_bf16(ahi[kt], bf[kt][nt][0],
                                                      acc, 0, 0, 0);
        acc = __builtin_amdgcn_mfma_f32_16x16x32_bf16(ahi[kt], bf[kt][nt][1],
                                                      acc, 0, 0, 0);
        acc = __builtin_amdgcn_mfma_f32_16x16x32_bf16(alo[kt], bf[kt][nt][0],
                                                      acc, 0, 0, 0);
      }
#pragma unroll
      for (int r = 0; r < 4; r++) {
        int grow = i0 + quad * 4 + r;
        if (grow < N) {
          float v = acc[r];
          h[(size_t)grow * D + nt * 16 + lo4] = v;
          psum[nt] += v;
          psq[nt] += v * v;
        }
      }
    }
  }

  // Stats: cross-quad reduce (lanes with same col), then block LDS reduce,
  // then one atomic per column per block.
#pragma unroll
  for (int nt = 0; nt < 4; nt++) {
    float s = psum[nt], q = psq[nt];
    s += __shfl_xor(s, 16); s += __shfl_xor(s, 32);
    q += __shfl_xor(q, 16); q += __shfl_xor(q, 32);
    if (lane < 16) { ssum[wvid][nt * 16 + lane] = s; ssq[wvid][nt * 16 + lane] = q; }
  }
  __syncthreads();
  if (tid < 64) {
    atomicAdd(&stats[tid], ssum[0][tid] + ssum[1][tid] + ssum[2][tid] + ssum[3][tid]);
  } else if (tid < 128) {
    int c = tid - 64;
    atomicAdd(&stats[D + c], ssq[0][c] + ssq[1][c] + ssq[2][c] + ssq[3][c]);
  }
}

// ---------------------------------------------------------------------------
__global__ void bn_finalize_kernel(const float* __restrict__ stats,
                                   const float* __restrict__ gamma,
                                   const float* __restrict__ beta,
                                   float* __restrict__ scsh, float fN) {
  int j = threadIdx.x;  // 64 threads
  float mean = stats[j] / fN;
  float var = stats[D + j] / fN - mean * mean;
  float sc = gamma[j] * rsqrtf(var + BN_EPS);
  scsh[j] = sc;
  scsh[D + j] = beta[j] - mean * sc;
}

// ---------------------------------------------------------------------------
__global__ __launch_bounds__(256) void norm_relu_kernel(
    const float* __restrict__ h, const float* __restrict__ scsh,
    float* __restrict__ xout, int n) {
  int tid = blockIdx.x * 256 + threadIdx.x;
  int base = tid * 4;
  if (base >= n) return;
  int j = base & 63;
  float4 hv = *(const float4*)&h[base];
  float4 sc = *(const float4*)&scsh[j];
  float4 sh = *(const float4*)&scsh[D + j];
  float4 o;
  o.x = fmaxf(hv.x * sc.x + sh.x, 0.f);
  o.y = fmaxf(hv.y * sc.y + sh.y, 0.f);
  o.z = fmaxf(hv.z * sc.z + sh.z, 0.f);
  o.w = fmaxf(hv.w * sc.w + sh.w, 0.f);
  *(float4*)&xout[base] = o;
}

// ---------------------------------------------------------------------------
__global__ __launch_bounds__(256) void norm_relu_pool_kernel(
    const float* __restrict__ h, const float* __restrict__ scsh,
    const int* __restrict__ batch, float* __restrict__ pooled, int N) {
  int j = threadIdx.x & 63;
  int q = threadIdx.x >> 6;
  int i0 = blockIdx.x * 256;
  float sc = scsh[j], sh = scsh[D + j];
  int curg = -1;
  float acc = 0.f;
  for (int r = q; r < 256; r += 4) {
    int i = i0 + r;
    if (i >= N) break;
    int b = batch[i];
    float v = fmaxf(h[i * D + j] * sc + sh, 0.f);
    if (b != curg) {
      if (curg >= 0) atomicAdd(&pooled[curg * D + j], acc);
      curg = b;
      acc = v;
    } else {
      acc += v;
    }
  }
  if (curg >= 0) atomicAdd(&pooled[curg * D + j], acc);
}

// ---------------------------------------------------------------------------
__global__ void counts_kernel(const int* __restrict__ batch,
                              float* __restrict__ counts, int N) {
  int g = threadIdx.x;
  if (g >= NGRAPH) return;
  int lo = 0, hi = N;
  while (lo < hi) { int m = (lo + hi) >> 1; if (batch[m] < g) lo = m + 1; else hi = m; }
  int start = lo;
  lo = 0; hi = N;
  while (lo < hi) { int m = (lo + hi) >> 1; if (batch[m] <= g) lo = m + 1; else hi = m; }
  counts[g] = (float)(lo - start);
}

// ---------------------------------------------------------------------------
__global__ void cls_kernel(const float* __restrict__ pooled,
                           const float* __restrict__ counts,
                           const float* __restrict__ Wcls,
                           const float* __restrict__ bcls,
                           float* __restrict__ out) {
  int tid = blockIdx.x * blockDim.x + threadIdx.x;
  if (tid >= NGRAPH * NCLS) return;
  int g = tid / NCLS, c = tid % NCLS;
  float inv = 1.f / fmaxf(counts[g], 1.f);
  float acc = bcls[c];
#pragma unroll 8
  for (int k = 0; k < D; k++) acc += pooled[g * D + k] * inv * Wcls[k * NCLS + c];
  out[g * NCLS + c] = acc;
}

// ---------------------------------------------------------------------------
extern "C" void kernel_launch(void* const* d_in, const int* in_sizes, int n_in,
                              void* d_out, int out_size, void* d_ws, size_t ws_size,
                              hipStream_t stream) {
  const float* x      = (const float*)d_in[0];
  const int*   ei     = (const int*)d_in[1];
  const int*   batch  = (const int*)d_in[2];
  const float* W_rel  = (const float*)d_in[3];
  const float* b_rel  = (const float*)d_in[4];
  const float* W_root = (const float*)d_in[5];
  const float* gamma  = (const float*)d_in[6];
  const float* beta   = (const float*)d_in[7];
  const float* W_cls  = (const float*)d_in[8];
  const float* b_cls  = (const float*)d_in[9];
  float* out = (float*)d_out;

  int E = in_sizes[1] / 2;
  int N = in_sizes[2];
  size_t nd = (size_t)N * D;
  int nb = (N + 1023) / 1024;

  // Workspace layout.
  float* bufA    = (float*)d_ws;             // N*D: gather target / h in place
  float* bufB    = bufA + nd;                // N*D: normalized x ping-pong
  float* stats   = bufB + nd;                // 2*D
  float* scsh    = stats + 2 * D;            // 2*D
  float* pooled  = scsh + 2 * D;             // NGRAPH*D
  float* counts  = pooled + NGRAPH * D;      // NGRAPH
  ushort* wfrag  = (ushort*)(counts + NGRAPH);  // 3*16384 ushorts (96 KB)
  int* deg       = (int*)(wfrag + 3 * 16384);
  int* cursor    = deg + N;
  int* row_start = cursor + N;               // N+1
  int* bsum      = row_start + N + 1;        // nb
  int* csr_src   = bsum + ((nb + 3) & ~3);   // E

  // ---- Once-per-call prep ----
  hipMemsetAsync(deg, 0, 2 * N * sizeof(int), stream);  // deg + cursor
  hipMemsetAsync(pooled, 0, (NGRAPH * D + NGRAPH) * sizeof(float), stream);
  hist_kernel<<<(E + 255) / 256, 256, 0, stream>>>(ei, deg, E);
  scan1_kernel<<<nb, 256, 0, stream>>>(deg, row_start, bsum, N);
  scan2_kernel<<<1, 1024, 0, stream>>>(bsum, row_start, nb, E, N);
  scan3_kernel<<<nb, 256, 0, stream>>>(row_start, bsum, N);
  fill_kernel<<<(E + 255) / 256, 256, 0, stream>>>(ei, row_start, cursor, csr_src, E);
  wsplit_kernel<<<3, 256, 0, stream>>>(W_rel, W_root, wfrag);

  // ---- Layers ----
  const int MM_BLOCKS = 512;
  const int MM_WAVES = MM_BLOCKS * 4;
  int ntiles = (N + 15) / 16;
  const float* xin = x;
  for (int l = 0; l < 3; l++) {
    hipMemsetAsync(stats, 0, 2 * D * sizeof(float), stream);

    gather_kernel<<<(N + 3) / 4, 256, 0, stream>>>(xin, csr_src, row_start, bufA, N);

    mm_mfma_kernel<<<MM_BLOCKS, 256, 0, stream>>>(
        bufA, xin, wfrag + l * 16384, b_rel + l * D, bufA /* in place */,
        stats, N, ntiles, MM_WAVES);

    bn_finalize_kernel<<<1, 64, 0, stream>>>(stats, gamma + l * D, beta + l * D,
                                             scsh, (float)N);

    if (l < 2) {
      int n = N * D;
      norm_relu_kernel<<<(n / 4 + 255) / 256, 256, 0, stream>>>(bufA, scsh, bufB, n);
      xin = bufB;
    } else {
      norm_relu_pool_kernel<<<(N + 255) / 256, 256, 0, stream>>>(bufA, scsh, batch,
                                                                 pooled, N);
    }
  }

  counts_kernel<<<1, 128, 0, stream>>>(batch, counts, N);
  cls_kernel<<<(NGRAPH * NCLS + 255) / 256, 256, 0, stream>>>(pooled, counts,
                                                              W_cls, b_cls, out);
}